// Round 4
// baseline (305.323 us; speedup 1.0000x reference)
//
#include <hip/hip_runtime.h>

// VQ-VAE quantize + EMA update, MI355X.
// R12: (a) dist_kernel: 2048 blocks x 64 rows (wave = ONE 16-row tile, was
//     two). Same math, same MFMA chain order per row (bit-identical); halves
//     per-wave state so 8 blocks/CU x 4 waves can be co-resident (R11 showed
//     Occupancy 31%, grid-limited at 4 blocks/CU; latency not covered).
//     (b) scatter_kernel: blockIdx remap so all 8 octant-blocks of one rb
//     land on the SAME XCD (bid%8 const) -> kills 8x L2-fill of shared x
//     rows; 1024 threads (16 waves/CU, was 8) for L3-latency hiding.
//     Partial slabs written by (rb*8+oct) so finalize2 is unchanged.
//     (c) recheck grid 512 -> 1024.

#define N_ROWS 131072
#define DIM    64
#define NEMB   1024
#define FLAG_CAP 131072
#define TAU 0.02f
#define NRANGE 32

static constexpr float DECAYF = 0.99f;
static constexpr float OMDF   = (float)(1.0 - 0.99);
static constexpr float EPSF   = 1e-5f;
static constexpr float NEPSF  = (float)(1024 * 1e-5);

typedef __attribute__((ext_vector_type(8))) short short8;
typedef __attribute__((ext_vector_type(4))) float f32x4;

static __device__ __forceinline__ unsigned short f2bf(float f) {
    unsigned int u = __builtin_bit_cast(unsigned int, f);
    unsigned int r = (u + 0x7FFFu + ((u >> 16) & 1u)) >> 16;   // RNE
    return (unsigned short)r;
}
static __device__ __forceinline__ float bf2f(unsigned short h) {
    unsigned int u = ((unsigned int)h) << 16;
    return __builtin_bit_cast(float, u);
}

// ws layout (float offsets)
#define WS_ESUM    0         // 65536 (atomic-fallback target)
#define WS_CNTF    65536     // 1024  (atomic-fallback counts)
#define WS_DIFF    66560     // 1
#define WS_FLAGCNT 66561     // 1 (int)
#define WS_N       66562     // 1
#define WS_EE      66564     // 1024
#define WS_EMBEDT  67588     // 65536 (16B aligned)
#define WS_IDX     133124    // 131072 (int)
#define WS_FLAGLST 264196    // 131072 (int)
#define WS_BFRAG   395268    // 65536 floats = 256 KB (16B aligned)
#define WS_CNTPART 460804    // 32768 (NRANGE x 1024)
#define WS_PART    493572    // NRANGE x 65536 = 2097152 floats (16B aligned)
#define WS_NEED_BYTES ((size_t)(WS_PART + NRANGE * 65536) * 4)

// ---------------- prep: embedT, ee, hi/lo fragments of B' = -2*embed
__global__ void prep_kernel(const float* __restrict__ embed,
                            float* __restrict__ embedT,
                            float* __restrict__ ee,
                            uint4* __restrict__ BfragG) {
    int tid = blockIdx.x * 256 + threadIdx.x;      // 0..16383
    for (int i = 0; i < 4; ++i) {
        int id = i * 16384 + tid;
        int d = id >> 10, e = id & 1023;
        embedT[e * 64 + d] = embed[id];
    }
    if (tid < NEMB) {
        float s = 0.f;
        for (int d = 0; d < DIM; ++d) {
            float v = embed[d * 1024 + tid];
            s = fmaf(v, v, s);
        }
        ee[tid] = s;
    }
    int fid  = tid >> 6;            // 0..255
    int lane = tid & 63;
    int hl = fid & 1, kt = (fid >> 1) & 1, ct = fid >> 2;
    int col = ct * 16 + (lane & 15);
    int k0  = kt * 32 + (lane >> 4) * 8;
    unsigned short u[8];
    #pragma unroll
    for (int j = 0; j < 8; ++j) {
        float v = -2.0f * embed[(k0 + j) * 1024 + col];
        unsigned short h = f2bf(v);
        if (hl) h = f2bf(v - bf2f(h));
        u[j] = h;
    }
    uint4 wv;
    wv.x = (unsigned)u[0] | ((unsigned)u[1] << 16);
    wv.y = (unsigned)u[2] | ((unsigned)u[3] << 16);
    wv.z = (unsigned)u[4] | ((unsigned)u[5] << 16);
    wv.w = (unsigned)u[6] | ((unsigned)u[7] << 16);
    BfragG[fid * 64 + lane] = wv;
}

// ---------------- dist: hi/lo MFMA + best2 + quantize + diff
// R12: 2048 blocks x 64 rows; each wave = one 16-row MFMA tile. B fragments
// streamed from L2 into registers (1-group rotating prefetch), no main-loop
// barriers. MFMA chain order per row unchanged => bit-identical results.
__global__ __launch_bounds__(256) void dist_kernel(
        const float* __restrict__ x, const uint4* __restrict__ BfragG,
        const float* __restrict__ ee, const float* __restrict__ embedT,
        float* __restrict__ out_q, float* __restrict__ out_ind,
        int* __restrict__ ws_idx, float* __restrict__ ws_diff,
        int* __restrict__ ws_flagcnt, int* __restrict__ ws_flaglist) {
    __shared__ float sEE[1024];           // 4 KB
    __shared__ int   sIdx[64];
    __shared__ float red[4];

    const int t = threadIdx.x;
    const int w = t >> 6, lane = t & 63;
    const int quad = lane >> 4, wl = lane & 15;
    const int rbase = blockIdx.x * 64;

    short8 a_hi[2], a_lo[2];
    {
        int row = rbase + w * 16 + wl;
        #pragma unroll
        for (int kt = 0; kt < 2; ++kt) {
            const float* px = x + (size_t)row * 64 + kt * 32 + quad * 8;
            float4 v0 = *(const float4*)px;
            float4 v1 = *(const float4*)(px + 4);
            float vv[8] = {v0.x, v0.y, v0.z, v0.w, v1.x, v1.y, v1.z, v1.w};
            short8 ah, al;
            #pragma unroll
            for (int j = 0; j < 8; ++j) {
                unsigned short h = f2bf(vv[j]);
                ah[j] = (short)h;
                al[j] = (short)f2bf(vv[j] - bf2f(h));
            }
            a_hi[kt] = ah; a_lo[kt] = al;
        }
    }

    // ee -> LDS once (broadcast reads in the loop, conflict-free)
    for (int i = t; i < 1024; i += 256) sEE[i] = ee[i];

    float b1[4], b2[4];
    int   i1[4];
    #pragma unroll
    for (int s = 0; s < 4; ++s) { b1[s] = 3.4e38f; b2[s] = 3.4e38f; i1[s] = 0; }

    const f32x4 zacc = {0.f, 0.f, 0.f, 0.f};

    __syncthreads();                      // sEE visible; only barrier pre-loop

    // main loop: 64 col-groups of 16 cols; B frags direct from L2.
    const uint4* bg = BfragG + lane;
    uint4 nb0 = bg[0], nb1 = bg[64], nb2 = bg[128], nb3 = bg[192];
    for (int g = 0; g < 64; ++g) {
        uint4 c_b0 = nb0, c_b1 = nb1, c_b2 = nb2, c_b3 = nb3;
        if (g < 63) {                     // rotating 1-group prefetch
            const uint4* p = bg + (g + 1) * 256;
            nb0 = p[0]; nb1 = p[64]; nb2 = p[128]; nb3 = p[192];
        }
        short8 bh0 = __builtin_bit_cast(short8, c_b0);
        short8 bl0 = __builtin_bit_cast(short8, c_b1);
        short8 bh1 = __builtin_bit_cast(short8, c_b2);
        short8 bl1 = __builtin_bit_cast(short8, c_b3);
        int col = g * 16 + wl;
        float eec = sEE[col];
        {
            f32x4 c0 = __builtin_amdgcn_mfma_f32_16x16x32_bf16(a_lo[0], bh0, zacc, 0, 0, 0);
            f32x4 c1 = __builtin_amdgcn_mfma_f32_16x16x32_bf16(a_lo[1], bh1, zacc, 0, 0, 0);
            c0 = __builtin_amdgcn_mfma_f32_16x16x32_bf16(a_hi[0], bl0, c0, 0, 0, 0);
            c1 = __builtin_amdgcn_mfma_f32_16x16x32_bf16(a_hi[1], bl1, c1, 0, 0, 0);
            c0 = __builtin_amdgcn_mfma_f32_16x16x32_bf16(a_hi[0], bh0, c0, 0, 0, 0);
            c1 = __builtin_amdgcn_mfma_f32_16x16x32_bf16(a_hi[1], bh1, c1, 0, 0, 0);
            #pragma unroll
            for (int reg = 0; reg < 4; ++reg) {
                float s = c0[reg] + c1[reg] + eec;          // v_add3_f32
                bool lt = s < b1[reg];
                b2[reg] = fminf(fmaxf(s, b1[reg]), b2[reg]);
                i1[reg] = lt ? col : i1[reg];
                b1[reg] = fminf(s, b1[reg]);
            }
        }
    }

    for (int m = 1; m < 16; m <<= 1) {
        #pragma unroll
        for (int s = 0; s < 4; ++s) {
            float ob1 = __shfl_xor(b1[s], m);
            int   oi1 = __shfl_xor(i1[s], m);
            float ob2 = __shfl_xor(b2[s], m);
            if (ob1 < b1[s] || (ob1 == b1[s] && oi1 < i1[s])) {
                b2[s] = fminf(b1[s], ob2); b1[s] = ob1; i1[s] = oi1;
            } else {
                b2[s] = fminf(b2[s], ob1);
            }
        }
    }
    if (wl == 0) {
        #pragma unroll
        for (int s = 0; s < 4; ++s) {
            int rloc = w * 16 + quad * 4 + s;
            int row = rbase + rloc;
            sIdx[rloc] = i1[s];
            ws_idx[row] = i1[s];
            out_ind[row] = (float)i1[s];
            if (b2[s] - b1[s] < TAU) {
                int pos = atomicAdd(ws_flagcnt, 1);
                if (pos < FLAG_CAP) ws_flaglist[pos] = row;
            }
        }
    }
    __syncthreads();

    {
        int r = t >> 2, hh = t & 3;       // 4 threads per row, 16 floats each
        int e = sIdx[r];
        const float4* et = (const float4*)(embedT + e * 64 + hh * 16);
        const float4* xr = (const float4*)(x + (size_t)(rbase + r) * 64 + hh * 16);
        float4*       qo = (float4*)(out_q + (size_t)(rbase + r) * 64 + hh * 16);
        float dsum = 0.f;
        #pragma unroll
        for (int v = 0; v < 4; ++v) {
            float4 q4 = et[v];
            float4 x4 = xr[v];
            float dx = q4.x - x4.x, dy = q4.y - x4.y, dz = q4.z - x4.z, dw = q4.w - x4.w;
            float4 o;
            o.x = x4.x + dx; o.y = x4.y + dy; o.z = x4.z + dz; o.w = x4.w + dw;
            qo[v] = o;
            dsum += dx * dx + dy * dy + dz * dz + dw * dw;
        }
        for (int o2 = 32; o2 > 0; o2 >>= 1) dsum += __shfl_down(dsum, o2);
        if (lane == 0) red[w] = dsum;
        __syncthreads();
        if (t == 0) atomicAdd(ws_diff, red[0] + red[1] + red[2] + red[3]);
    }
}

// ---------------- recheck: tiled exact fp32 re-argmin (wave-parallel form)
__global__ __launch_bounds__(256) void recheck_kernel(
        const float* __restrict__ x, const float* __restrict__ embed,
        const float* __restrict__ embedT, const float* __restrict__ ee,
        const int* __restrict__ flagcnt, const int* __restrict__ flaglist,
        int* __restrict__ ws_idx, float* __restrict__ out_ind,
        float* __restrict__ out_q, float* __restrict__ ws_diff) {
    __shared__ float sx[8][64];
    __shared__ float sff[8];
    __shared__ int   srow[8];
    __shared__ float sbd[8][256];
    __shared__ int   sbi[8][256];
    const int t = threadIdx.x;
    const int w = t >> 6, lane = t & 63;
    int cnt = *flagcnt;
    if (cnt > FLAG_CAP) cnt = FLAG_CAP;
    int ntiles = (cnt + 7) >> 3;
    for (int tile = blockIdx.x; tile < ntiles; tile += gridDim.x) {
        int base = tile * 8;
        int nr = cnt - base; if (nr > 8) nr = 8;
        __syncthreads();                               // LDS reuse guard
        if (t < nr) srow[t] = flaglist[base + t];
        __syncthreads();
        for (int l = t; l < nr * 64; l += 256)
            sx[l >> 6][l & 63] = x[(size_t)srow[l >> 6] * 64 + (l & 63)];
        __syncthreads();
        if (t < nr) {
            float ff = 0.f;
            for (int k = 0; k < 64; ++k) ff = fmaf(sx[t][k], sx[t][k], ff);
            sff[t] = ff;
        }
        float acc[8][4];
        #pragma unroll
        for (int r = 0; r < 8; ++r)
            #pragma unroll
            for (int j = 0; j < 4; ++j) acc[r][j] = 0.f;
        int c0 = t * 4;
        for (int k = 0; k < 64; ++k) {
            float4 e4 = *(const float4*)(embed + k * 1024 + c0);
            #pragma unroll
            for (int r = 0; r < 8; ++r) {
                float xk = sx[r][k];
                acc[r][0] = fmaf(xk, e4.x, acc[r][0]);
                acc[r][1] = fmaf(xk, e4.y, acc[r][1]);
                acc[r][2] = fmaf(xk, e4.z, acc[r][2]);
                acc[r][3] = fmaf(xk, e4.w, acc[r][3]);
            }
        }
        __syncthreads();                               // sff visible
        #pragma unroll
        for (int r = 0; r < 8; ++r) {
            float ff = sff[r];
            float bd = 3.4e38f; int bi = 0;
            #pragma unroll
            for (int j = 0; j < 4; ++j) {
                float d = (ff - 2.f * acc[r][j]) + ee[c0 + j];
                if (d < bd) { bd = d; bi = c0 + j; }
            }
            sbd[r][t] = bd; sbi[r][t] = bi;
        }
        __syncthreads();
        #pragma unroll
        for (int rr = 0; rr < 2; ++rr) {
            int r = w * 2 + rr;
            if (r < nr) {
                float bd = sbd[r][lane]; int bi = sbi[r][lane];
                #pragma unroll
                for (int k2 = 1; k2 < 4; ++k2) {
                    float od = sbd[r][lane + 64 * k2];
                    int   oi = sbi[r][lane + 64 * k2];
                    if (od < bd || (od == bd && oi < bi)) { bd = od; bi = oi; }
                }
                for (int m = 32; m > 0; m >>= 1) {
                    float od = __shfl_xor(bd, m);
                    int   oi = __shfl_xor(bi, m);
                    if (od < bd || (od == bd && oi < bi)) { bd = od; bi = oi; }
                }
                int row = srow[r];
                int oi_old = ws_idx[row];               // broadcast load
                if (bi != oi_old) {
                    float xv = sx[r][lane];
                    float dn   = embedT[bi * 64 + lane] - xv;
                    float dold = embedT[oi_old * 64 + lane] - xv;
                    out_q[(size_t)row * 64 + lane] = xv + dn;
                    float delta = dn * dn - dold * dold;
                    for (int o = 32; o > 0; o >>= 1) delta += __shfl_down(delta, o);
                    if (lane == 0) {
                        ws_idx[row] = bi;
                        out_ind[row] = (float)bi;
                        atomicAdd(ws_diff, delta);
                    }
                }
            }
        }
    }
}

// ---------------- scatter: 32 ranges x 8 dim-octants; LDS hist [1024 codes][8 dims]
// R12: blockIdx remap co-locates the 8 octant-blocks of one rb on the same
// XCD (bid%8 == rb&7); 1024 threads = 16 waves, 32 iters each. Partial slab
// written at (rb*8+oct) so finalize2 layout is unchanged.
__global__ __launch_bounds__(1024) void scatter_kernel(
        const int* __restrict__ idx, const float* __restrict__ x,
        float* __restrict__ part_or_esum, float* __restrict__ cntp_or_cntf,
        int use_atomic) {
    __shared__ float shist[8192];         // [1024 codes][8 dims] = 32 KB
    __shared__ float scnt[1024];          // used by oct==0 blocks
    const int t = threadIdx.x;
    // bid = (rb&7) + 8*oct + 64*(rb>>3)  (bijective on 0..255)
    const int bid = blockIdx.x;
    const int oct = (bid >> 3) & 7;
    const int rb  = (bid & 7) | ((bid >> 6) << 3);
    const int sid = rb * 8 + oct;                              // slab index
    const int w = t >> 6, lane = t & 63;
    const int g = lane >> 3, d = lane & 7;                     // 8 rows x 8 dims

    for (int i = t; i < 8192; i += 1024) shist[i] = 0.f;
    if (oct == 0) { if (t < 1024) scnt[t] = 0.f; }
    __syncthreads();

    const int row0 = rb * 4096 + w * 256;
    int rcur = row0 + g;
    int e_n = idx[rcur];
    float x_n = x[(size_t)rcur * 64 + oct * 8 + d];
    for (int it = 0; it < 32; ++it) {                  // 32 x 8 rows per wave
        int e = e_n; float xv = x_n;
        int rnext = rcur + 8;
        if (it < 31) {                                 // prefetch next iteration
            e_n = idx[rnext];
            x_n = x[(size_t)rnext * 64 + oct * 8 + d];
        }
        rcur = rnext;
        atomicAdd(&shist[e * 8 + d], xv);
        if (oct == 0 && d == 0) atomicAdd(&scnt[e], 1.0f);
    }
    __syncthreads();

    if (!use_atomic) {
        float* dst = part_or_esum + (size_t)sid * 8192;
        for (int out = t; out < 8192; out += 1024)     // out = dd*1024 + e
            dst[out] = shist[(out & 1023) * 8 + (out >> 10)];
        if (oct == 0) {
            float* cdst = cntp_or_cntf + rb * 1024;
            if (t < 1024) cdst[t] = scnt[t];
        }
    } else {
        for (int out = t; out < 8192; out += 1024) {
            float v = shist[(out & 1023) * 8 + (out >> 10)];
            if (v != 0.f)
                atomicAdd(&part_or_esum[(oct * 8 + (out >> 10)) * 1024 + (out & 1023)], v);
        }
        if (oct == 0) {
            if (t < 1024) {
                float c = scnt[t];
                if (c != 0.f) atomicAdd(&cntp_or_cntf[t], c);
            }
        }
    }
}

// ---------------- finalize1: counts reduce + new_cluster_size, n, diff
__global__ __launch_bounds__(1024) void finalize1(
        const float* __restrict__ cluster_size, const float* __restrict__ cntp,
        int nrb, const float* __restrict__ ws_diff, float* __restrict__ out_diff,
        float* __restrict__ out_ncs, float* __restrict__ ws_n) {
    int t = threadIdx.x;
    float c = 0.f;
    for (int k = 0; k < nrb; ++k) c += cntp[k * 1024 + t];
    float ncs = DECAYF * cluster_size[t] + OMDF * c;
    out_ncs[t] = ncs;
    __shared__ float sred[16];
    float v = ncs;
    for (int o = 32; o > 0; o >>= 1) v += __shfl_down(v, o);
    if ((t & 63) == 0) sred[t >> 6] = v;
    __syncthreads();
    if (t == 0) {
        float n = 0.f;
        for (int i = 0; i < 16; ++i) n += sred[i];
        ws_n[0] = n;
        out_diff[0] = ws_diff[0] * (1.0f / 8388608.0f);   // /2^23 exact
    }
}

// ---------------- finalize2: partials reduce + new_embed_avg, new_embed
__global__ __launch_bounds__(256) void finalize2(
        const float* __restrict__ embed_avg, const float* __restrict__ part,
        int nrb, const float* __restrict__ out_ncs, const float* __restrict__ ws_n,
        float* __restrict__ out_nea, float* __restrict__ out_ne) {
    int j = blockIdx.x * 256 + threadIdx.x;      // < 65536 = dim*1024 + code
    float es = 0.f;
    for (int k = 0; k < nrb; ++k) es += part[(size_t)k * 65536 + j];
    float n = ws_n[0];
    float nea = DECAYF * embed_avg[j] + OMDF * es;
    out_nea[j] = nea;
    float ncs = out_ncs[j & 1023];
    float cs = (ncs + EPSF) / (n + NEPSF) * n;
    out_ne[j] = nea / cs;
}

extern "C" void kernel_launch(void* const* d_in, const int* in_sizes, int n_in,
                              void* d_out, int out_size, void* d_ws, size_t ws_size,
                              hipStream_t stream) {
    const float* x            = (const float*)d_in[0];
    const float* embed        = (const float*)d_in[1];
    const float* cluster_size = (const float*)d_in[2];
    const float* embed_avg    = (const float*)d_in[3];

    float* out = (float*)d_out;
    float* out_q    = out;                       // 8388608
    float* out_diff = out + 8388608;             // 1
    float* out_ind  = out + 8388609;             // 131072
    float* out_ncs  = out + 8519681;             // 1024
    float* out_nea  = out + 8520705;             // 65536
    float* out_ne   = out + 8586241;             // 65536

    float* ws = (float*)d_ws;
    float* ws_esum     = ws + WS_ESUM;
    float* ws_cntf     = ws + WS_CNTF;
    float* ws_diff     = ws + WS_DIFF;
    int*   ws_flagcnt  = (int*)(ws + WS_FLAGCNT);
    float* ws_n        = ws + WS_N;
    float* ws_ee       = ws + WS_EE;
    float* ws_embedT   = ws + WS_EMBEDT;
    int*   ws_idx      = (int*)(ws + WS_IDX);
    int*   ws_flaglist = (int*)(ws + WS_FLAGLST);
    uint4* ws_Bfrag    = (uint4*)(ws + WS_BFRAG);
    float* ws_cntpart  = ws + WS_CNTPART;
    float* ws_part     = ws + WS_PART;

    const int use_part = (ws_size >= WS_NEED_BYTES) ? 1 : 0;

    if (use_part) {
        hipMemsetAsync(ws + WS_DIFF, 0, 8, stream);          // diff + flagcnt only
    } else {
        hipMemsetAsync(d_ws, 0, (size_t)(WS_FLAGCNT + 1) * 4, stream);
    }

    prep_kernel<<<64, 256, 0, stream>>>(embed, ws_embedT, ws_ee, ws_Bfrag);
    dist_kernel<<<N_ROWS / 64, 256, 0, stream>>>(x, ws_Bfrag, ws_ee, ws_embedT,
                                                 out_q, out_ind, ws_idx, ws_diff,
                                                 ws_flagcnt, ws_flaglist);
    recheck_kernel<<<1024, 256, 0, stream>>>(x, embed, ws_embedT, ws_ee,
                                             ws_flagcnt, ws_flaglist,
                                             ws_idx, out_ind, out_q, ws_diff);
    scatter_kernel<<<NRANGE * 8, 1024, 0, stream>>>(
        ws_idx, x,
        use_part ? ws_part : ws_esum,
        use_part ? ws_cntpart : ws_cntf,
        use_part ? 0 : 1);
    finalize1<<<1, 1024, 0, stream>>>(cluster_size,
                                      use_part ? ws_cntpart : ws_cntf,
                                      use_part ? NRANGE : 1,
                                      ws_diff, out_diff, out_ncs, ws_n);
    finalize2<<<256, 256, 0, stream>>>(embed_avg,
                                       use_part ? ws_part : ws_esum,
                                       use_part ? NRANGE : 1,
                                       out_ncs, ws_n, out_nea, out_ne);
}

// Round 5
// 268.311 us; speedup vs baseline: 1.1379x; 1.1379x over previous
//
#include <hip/hip_runtime.h>

// VQ-VAE quantize + EMA update, MI355X.
// R13: (a) dist_kernel: 512 blocks x 256 rows, each wave = FOUR 16-row tiles
//     (R12 showed more waves+less compute/load regresses; R11->R12 isolates
//     L2 B-delivery as the bound). Halves chip-wide B L2 traffic (1.0->0.5GB)
//     and doubles MFMA per load. (b) staggered group order (goff = bid&63):
//     concurrent blocks read DIFFERENT 4KB B-chunks -> spreads L2 hot-set
//     over the full 256KB. Order-safe: (b1,b2) = two smallest of multiset is
//     order-independent; exact ties give b2==b1 -> flagged -> recheck fixes
//     index. Same per-element math => identical numerics. (c) b2 update via
//     v_med3_f32. (d) recheck: 16-row tiles (halves per-row embed re-reads).
//     scatter unchanged from R12.

#define N_ROWS 131072
#define DIM    64
#define NEMB   1024
#define FLAG_CAP 131072
#define TAU 0.02f
#define NRANGE 32

static constexpr float DECAYF = 0.99f;
static constexpr float OMDF   = (float)(1.0 - 0.99);
static constexpr float EPSF   = 1e-5f;
static constexpr float NEPSF  = (float)(1024 * 1e-5);

typedef __attribute__((ext_vector_type(8))) short short8;
typedef __attribute__((ext_vector_type(4))) float f32x4;

static __device__ __forceinline__ unsigned short f2bf(float f) {
    unsigned int u = __builtin_bit_cast(unsigned int, f);
    unsigned int r = (u + 0x7FFFu + ((u >> 16) & 1u)) >> 16;   // RNE
    return (unsigned short)r;
}
static __device__ __forceinline__ float bf2f(unsigned short h) {
    unsigned int u = ((unsigned int)h) << 16;
    return __builtin_bit_cast(float, u);
}

// ws layout (float offsets)
#define WS_ESUM    0         // 65536 (atomic-fallback target)
#define WS_CNTF    65536     // 1024  (atomic-fallback counts)
#define WS_DIFF    66560     // 1
#define WS_FLAGCNT 66561     // 1 (int)
#define WS_N       66562     // 1
#define WS_EE      66564     // 1024
#define WS_EMBEDT  67588     // 65536 (16B aligned)
#define WS_IDX     133124    // 131072 (int)
#define WS_FLAGLST 264196    // 131072 (int)
#define WS_BFRAG   395268    // 65536 floats = 256 KB (16B aligned)
#define WS_CNTPART 460804    // 32768 (NRANGE x 1024)
#define WS_PART    493572    // NRANGE x 65536 = 2097152 floats (16B aligned)
#define WS_NEED_BYTES ((size_t)(WS_PART + NRANGE * 65536) * 4)

// ---------------- prep: embedT, ee, hi/lo fragments of B' = -2*embed
__global__ void prep_kernel(const float* __restrict__ embed,
                            float* __restrict__ embedT,
                            float* __restrict__ ee,
                            uint4* __restrict__ BfragG) {
    int tid = blockIdx.x * 256 + threadIdx.x;      // 0..16383
    for (int i = 0; i < 4; ++i) {
        int id = i * 16384 + tid;
        int d = id >> 10, e = id & 1023;
        embedT[e * 64 + d] = embed[id];
    }
    if (tid < NEMB) {
        float s = 0.f;
        for (int d = 0; d < DIM; ++d) {
            float v = embed[d * 1024 + tid];
            s = fmaf(v, v, s);
        }
        ee[tid] = s;
    }
    int fid  = tid >> 6;            // 0..255
    int lane = tid & 63;
    int hl = fid & 1, kt = (fid >> 1) & 1, ct = fid >> 2;
    int col = ct * 16 + (lane & 15);
    int k0  = kt * 32 + (lane >> 4) * 8;
    unsigned short u[8];
    #pragma unroll
    for (int j = 0; j < 8; ++j) {
        float v = -2.0f * embed[(k0 + j) * 1024 + col];
        unsigned short h = f2bf(v);
        if (hl) h = f2bf(v - bf2f(h));
        u[j] = h;
    }
    uint4 wv;
    wv.x = (unsigned)u[0] | ((unsigned)u[1] << 16);
    wv.y = (unsigned)u[2] | ((unsigned)u[3] << 16);
    wv.z = (unsigned)u[4] | ((unsigned)u[5] << 16);
    wv.w = (unsigned)u[6] | ((unsigned)u[7] << 16);
    BfragG[fid * 64 + lane] = wv;
}

// ---------------- dist: hi/lo MFMA + best2 + quantize + diff
// R13: 512 blocks x 256 rows; wave = four 16-row tiles. B streamed L2->reg,
// staggered group order, no main-loop barriers.
__global__ __launch_bounds__(256) void dist_kernel(
        const float* __restrict__ x, const uint4* __restrict__ BfragG,
        const float* __restrict__ ee, const float* __restrict__ embedT,
        float* __restrict__ out_q, float* __restrict__ out_ind,
        int* __restrict__ ws_idx, float* __restrict__ ws_diff,
        int* __restrict__ ws_flagcnt, int* __restrict__ ws_flaglist) {
    __shared__ float sEE[1024];           // 4 KB
    __shared__ int   sIdx[256];
    __shared__ float red[4];

    const int t = threadIdx.x;
    const int w = t >> 6, lane = t & 63;
    const int quad = lane >> 4, wl = lane & 15;
    const int rbase = blockIdx.x * 256;

    short8 a_hi[4][2], a_lo[4][2];
    #pragma unroll
    for (int rt = 0; rt < 4; ++rt) {
        int row = rbase + w * 64 + rt * 16 + wl;
        #pragma unroll
        for (int kt = 0; kt < 2; ++kt) {
            const float* px = x + (size_t)row * 64 + kt * 32 + quad * 8;
            float4 v0 = *(const float4*)px;
            float4 v1 = *(const float4*)(px + 4);
            float vv[8] = {v0.x, v0.y, v0.z, v0.w, v1.x, v1.y, v1.z, v1.w};
            short8 ah, al;
            #pragma unroll
            for (int j = 0; j < 8; ++j) {
                unsigned short h = f2bf(vv[j]);
                ah[j] = (short)h;
                al[j] = (short)f2bf(vv[j] - bf2f(h));
            }
            a_hi[rt][kt] = ah; a_lo[rt][kt] = al;
        }
    }

    // ee -> LDS once (broadcast reads in the loop, conflict-free)
    for (int i = t; i < 1024; i += 256) sEE[i] = ee[i];

    float b1[16], b2[16];
    int   i1[16];
    #pragma unroll
    for (int s = 0; s < 16; ++s) { b1[s] = 3.4e38f; b2[s] = 3.4e38f; i1[s] = 0; }

    const f32x4 zacc = {0.f, 0.f, 0.f, 0.f};

    __syncthreads();                      // sEE visible; only barrier pre-loop

    // main loop: 64 col-groups of 16 cols, visited in block-staggered order.
    const int goff = blockIdx.x & 63;
    int gv = goff;
    {
        // prime prefetch
    }
    const uint4* p0 = BfragG + gv * 256 + lane;
    uint4 nb0 = p0[0], nb1 = p0[64], nb2 = p0[128], nb3 = p0[192];
    for (int g = 0; g < 64; ++g) {
        uint4 c_b0 = nb0, c_b1 = nb1, c_b2 = nb2, c_b3 = nb3;
        const int col = gv * 16 + wl;
        if (g < 63) {                     // rotating 1-group prefetch
            gv = (gv + 1) & 63;
            const uint4* p = BfragG + gv * 256 + lane;
            nb0 = p[0]; nb1 = p[64]; nb2 = p[128]; nb3 = p[192];
        }
        short8 bh0 = __builtin_bit_cast(short8, c_b0);
        short8 bl0 = __builtin_bit_cast(short8, c_b1);
        short8 bh1 = __builtin_bit_cast(short8, c_b2);
        short8 bl1 = __builtin_bit_cast(short8, c_b3);
        float eec = sEE[col];
        #pragma unroll
        for (int rt = 0; rt < 4; ++rt) {
            f32x4 c0 = __builtin_amdgcn_mfma_f32_16x16x32_bf16(a_lo[rt][0], bh0, zacc, 0, 0, 0);
            f32x4 c1 = __builtin_amdgcn_mfma_f32_16x16x32_bf16(a_lo[rt][1], bh1, zacc, 0, 0, 0);
            c0 = __builtin_amdgcn_mfma_f32_16x16x32_bf16(a_hi[rt][0], bl0, c0, 0, 0, 0);
            c1 = __builtin_amdgcn_mfma_f32_16x16x32_bf16(a_hi[rt][1], bl1, c1, 0, 0, 0);
            c0 = __builtin_amdgcn_mfma_f32_16x16x32_bf16(a_hi[rt][0], bh0, c0, 0, 0, 0);
            c1 = __builtin_amdgcn_mfma_f32_16x16x32_bf16(a_hi[rt][1], bh1, c1, 0, 0, 0);
            #pragma unroll
            for (int reg = 0; reg < 4; ++reg) {
                float s = c0[reg] + c1[reg] + eec;
                int st = rt * 4 + reg;
                bool lt = s < b1[st];
                b2[st] = __builtin_amdgcn_fmed3f(s, b1[st], b2[st]);
                i1[st] = lt ? col : i1[st];
                b1[st] = fminf(s, b1[st]);
            }
        }
    }

    for (int m = 1; m < 16; m <<= 1) {
        #pragma unroll
        for (int s = 0; s < 16; ++s) {
            float ob1 = __shfl_xor(b1[s], m);
            int   oi1 = __shfl_xor(i1[s], m);
            float ob2 = __shfl_xor(b2[s], m);
            if (ob1 < b1[s] || (ob1 == b1[s] && oi1 < i1[s])) {
                b2[s] = fminf(b1[s], ob2); b1[s] = ob1; i1[s] = oi1;
            } else {
                b2[s] = fminf(b2[s], ob1);
            }
        }
    }
    if (wl == 0) {
        #pragma unroll
        for (int s = 0; s < 16; ++s) {
            int rt = s >> 2, reg = s & 3;
            int rloc = w * 64 + rt * 16 + quad * 4 + reg;
            int row = rbase + rloc;
            sIdx[rloc] = i1[s];
            ws_idx[row] = i1[s];
            out_ind[row] = (float)i1[s];
            if (b2[s] - b1[s] < TAU) {
                int pos = atomicAdd(ws_flagcnt, 1);
                if (pos < FLAG_CAP) ws_flaglist[pos] = row;
            }
        }
    }
    __syncthreads();

    {
        float dsum = 0.f;
        #pragma unroll
        for (int half = 0; half < 2; ++half) {
            int r = half * 128 + (t >> 1), hh = t & 1;
            int e = sIdx[r];
            const float4* et = (const float4*)(embedT + e * 64 + hh * 32);
            const float4* xr = (const float4*)(x + (size_t)(rbase + r) * 64 + hh * 32);
            float4*       qo = (float4*)(out_q + (size_t)(rbase + r) * 64 + hh * 32);
            #pragma unroll
            for (int v = 0; v < 8; ++v) {
                float4 q4 = et[v];
                float4 x4 = xr[v];
                float dx = q4.x - x4.x, dy = q4.y - x4.y, dz = q4.z - x4.z, dw = q4.w - x4.w;
                float4 o;
                o.x = x4.x + dx; o.y = x4.y + dy; o.z = x4.z + dz; o.w = x4.w + dw;
                qo[v] = o;
                dsum += dx * dx + dy * dy + dz * dz + dw * dw;
            }
        }
        for (int o2 = 32; o2 > 0; o2 >>= 1) dsum += __shfl_down(dsum, o2);
        if (lane == 0) red[w] = dsum;
        __syncthreads();
        if (t == 0) atomicAdd(ws_diff, red[0] + red[1] + red[2] + red[3]);
    }
}

// ---------------- recheck: tiled exact fp32 re-argmin, 16 rows/tile
__global__ __launch_bounds__(256) void recheck_kernel(
        const float* __restrict__ x, const float* __restrict__ embed,
        const float* __restrict__ embedT, const float* __restrict__ ee,
        const int* __restrict__ flagcnt, const int* __restrict__ flaglist,
        int* __restrict__ ws_idx, float* __restrict__ out_ind,
        float* __restrict__ out_q, float* __restrict__ ws_diff) {
    __shared__ float sx[16][64];
    __shared__ float sff[16];
    __shared__ int   srow[16];
    __shared__ float sbd[16][256];
    __shared__ int   sbi[16][256];
    const int t = threadIdx.x;
    const int w = t >> 6, lane = t & 63;
    int cnt = *flagcnt;
    if (cnt > FLAG_CAP) cnt = FLAG_CAP;
    int ntiles = (cnt + 15) >> 4;
    for (int tile = blockIdx.x; tile < ntiles; tile += gridDim.x) {
        int base = tile * 16;
        int nr = cnt - base; if (nr > 16) nr = 16;
        __syncthreads();                               // LDS reuse guard
        if (t < nr) srow[t] = flaglist[base + t];
        __syncthreads();
        for (int l = t; l < nr * 64; l += 256)
            sx[l >> 6][l & 63] = x[(size_t)srow[l >> 6] * 64 + (l & 63)];
        __syncthreads();
        if (t < nr) {
            float ff = 0.f;
            for (int k = 0; k < 64; ++k) ff = fmaf(sx[t][k], sx[t][k], ff);
            sff[t] = ff;
        }
        float acc[16][4];
        #pragma unroll
        for (int r = 0; r < 16; ++r)
            #pragma unroll
            for (int j = 0; j < 4; ++j) acc[r][j] = 0.f;
        int c0 = t * 4;
        for (int k = 0; k < 64; ++k) {
            float4 e4 = *(const float4*)(embed + k * 1024 + c0);
            #pragma unroll
            for (int r = 0; r < 16; ++r) {
                float xk = sx[r][k];
                acc[r][0] = fmaf(xk, e4.x, acc[r][0]);
                acc[r][1] = fmaf(xk, e4.y, acc[r][1]);
                acc[r][2] = fmaf(xk, e4.z, acc[r][2]);
                acc[r][3] = fmaf(xk, e4.w, acc[r][3]);
            }
        }
        __syncthreads();                               // sff visible
        #pragma unroll
        for (int r = 0; r < 16; ++r) {
            if (r < nr) {
                float ff = sff[r];
                float bd = 3.4e38f; int bi = 0;
                #pragma unroll
                for (int j = 0; j < 4; ++j) {
                    float d = (ff - 2.f * acc[r][j]) + ee[c0 + j];
                    if (d < bd) { bd = d; bi = c0 + j; }
                }
                sbd[r][t] = bd; sbi[r][t] = bi;
            }
        }
        __syncthreads();
        #pragma unroll
        for (int rr = 0; rr < 4; ++rr) {
            int r = w * 4 + rr;
            if (r < nr) {
                float bd = sbd[r][lane]; int bi = sbi[r][lane];
                #pragma unroll
                for (int k2 = 1; k2 < 4; ++k2) {
                    float od = sbd[r][lane + 64 * k2];
                    int   oi = sbi[r][lane + 64 * k2];
                    if (od < bd || (od == bd && oi < bi)) { bd = od; bi = oi; }
                }
                for (int m = 32; m > 0; m >>= 1) {
                    float od = __shfl_xor(bd, m);
                    int   oi = __shfl_xor(bi, m);
                    if (od < bd || (od == bd && oi < bi)) { bd = od; bi = oi; }
                }
                int row = srow[r];
                int oi_old = ws_idx[row];               // broadcast load
                if (bi != oi_old) {
                    float xv = sx[r][lane];
                    float dn   = embedT[bi * 64 + lane] - xv;
                    float dold = embedT[oi_old * 64 + lane] - xv;
                    out_q[(size_t)row * 64 + lane] = xv + dn;
                    float delta = dn * dn - dold * dold;
                    for (int o = 32; o > 0; o >>= 1) delta += __shfl_down(delta, o);
                    if (lane == 0) {
                        ws_idx[row] = bi;
                        out_ind[row] = (float)bi;
                        atomicAdd(ws_diff, delta);
                    }
                }
            }
        }
    }
}

// ---------------- scatter: 32 ranges x 8 dim-octants; LDS hist [1024 codes][8 dims]
// R12 form: blockIdx remap co-locates the 8 octant-blocks of one rb on the
// same XCD; 1024 threads = 16 waves, 32 iters each.
__global__ __launch_bounds__(1024) void scatter_kernel(
        const int* __restrict__ idx, const float* __restrict__ x,
        float* __restrict__ part_or_esum, float* __restrict__ cntp_or_cntf,
        int use_atomic) {
    __shared__ float shist[8192];         // [1024 codes][8 dims] = 32 KB
    __shared__ float scnt[1024];          // used by oct==0 blocks
    const int t = threadIdx.x;
    // bid = (rb&7) + 8*oct + 64*(rb>>3)  (bijective on 0..255)
    const int bid = blockIdx.x;
    const int oct = (bid >> 3) & 7;
    const int rb  = (bid & 7) | ((bid >> 6) << 3);
    const int sid = rb * 8 + oct;                              // slab index
    const int w = t >> 6, lane = t & 63;
    const int g = lane >> 3, d = lane & 7;                     // 8 rows x 8 dims

    for (int i = t; i < 8192; i += 1024) shist[i] = 0.f;
    if (oct == 0) { if (t < 1024) scnt[t] = 0.f; }
    __syncthreads();

    const int row0 = rb * 4096 + w * 256;
    int rcur = row0 + g;
    int e_n = idx[rcur];
    float x_n = x[(size_t)rcur * 64 + oct * 8 + d];
    for (int it = 0; it < 32; ++it) {                  // 32 x 8 rows per wave
        int e = e_n; float xv = x_n;
        int rnext = rcur + 8;
        if (it < 31) {                                 // prefetch next iteration
            e_n = idx[rnext];
            x_n = x[(size_t)rnext * 64 + oct * 8 + d];
        }
        rcur = rnext;
        atomicAdd(&shist[e * 8 + d], xv);
        if (oct == 0 && d == 0) atomicAdd(&scnt[e], 1.0f);
    }
    __syncthreads();

    if (!use_atomic) {
        float* dst = part_or_esum + (size_t)sid * 8192;
        for (int out = t; out < 8192; out += 1024)     // out = dd*1024 + e
            dst[out] = shist[(out & 1023) * 8 + (out >> 10)];
        if (oct == 0) {
            float* cdst = cntp_or_cntf + rb * 1024;
            if (t < 1024) cdst[t] = scnt[t];
        }
    } else {
        for (int out = t; out < 8192; out += 1024) {
            float v = shist[(out & 1023) * 8 + (out >> 10)];
            if (v != 0.f)
                atomicAdd(&part_or_esum[(oct * 8 + (out >> 10)) * 1024 + (out & 1023)], v);
        }
        if (oct == 0) {
            if (t < 1024) {
                float c = scnt[t];
                if (c != 0.f) atomicAdd(&cntp_or_cntf[t], c);
            }
        }
    }
}

// ---------------- finalize1: counts reduce + new_cluster_size, n, diff
__global__ __launch_bounds__(1024) void finalize1(
        const float* __restrict__ cluster_size, const float* __restrict__ cntp,
        int nrb, const float* __restrict__ ws_diff, float* __restrict__ out_diff,
        float* __restrict__ out_ncs, float* __restrict__ ws_n) {
    int t = threadIdx.x;
    float c = 0.f;
    for (int k = 0; k < nrb; ++k) c += cntp[k * 1024 + t];
    float ncs = DECAYF * cluster_size[t] + OMDF * c;
    out_ncs[t] = ncs;
    __shared__ float sred[16];
    float v = ncs;
    for (int o = 32; o > 0; o >>= 1) v += __shfl_down(v, o);
    if ((t & 63) == 0) sred[t >> 6] = v;
    __syncthreads();
    if (t == 0) {
        float n = 0.f;
        for (int i = 0; i < 16; ++i) n += sred[i];
        ws_n[0] = n;
        out_diff[0] = ws_diff[0] * (1.0f / 8388608.0f);   // /2^23 exact
    }
}

// ---------------- finalize2: partials reduce + new_embed_avg, new_embed
__global__ __launch_bounds__(256) void finalize2(
        const float* __restrict__ embed_avg, const float* __restrict__ part,
        int nrb, const float* __restrict__ out_ncs, const float* __restrict__ ws_n,
        float* __restrict__ out_nea, float* __restrict__ out_ne) {
    int j = blockIdx.x * 256 + threadIdx.x;      // < 65536 = dim*1024 + code
    float es = 0.f;
    for (int k = 0; k < nrb; ++k) es += part[(size_t)k * 65536 + j];
    float n = ws_n[0];
    float nea = DECAYF * embed_avg[j] + OMDF * es;
    out_nea[j] = nea;
    float ncs = out_ncs[j & 1023];
    float cs = (ncs + EPSF) / (n + NEPSF) * n;
    out_ne[j] = nea / cs;
}

extern "C" void kernel_launch(void* const* d_in, const int* in_sizes, int n_in,
                              void* d_out, int out_size, void* d_ws, size_t ws_size,
                              hipStream_t stream) {
    const float* x            = (const float*)d_in[0];
    const float* embed        = (const float*)d_in[1];
    const float* cluster_size = (const float*)d_in[2];
    const float* embed_avg    = (const float*)d_in[3];

    float* out = (float*)d_out;
    float* out_q    = out;                       // 8388608
    float* out_diff = out + 8388608;             // 1
    float* out_ind  = out + 8388609;             // 131072
    float* out_ncs  = out + 8519681;             // 1024
    float* out_nea  = out + 8520705;             // 65536
    float* out_ne   = out + 8586241;             // 65536

    float* ws = (float*)d_ws;
    float* ws_esum     = ws + WS_ESUM;
    float* ws_cntf     = ws + WS_CNTF;
    float* ws_diff     = ws + WS_DIFF;
    int*   ws_flagcnt  = (int*)(ws + WS_FLAGCNT);
    float* ws_n        = ws + WS_N;
    float* ws_ee       = ws + WS_EE;
    float* ws_embedT   = ws + WS_EMBEDT;
    int*   ws_idx      = (int*)(ws + WS_IDX);
    int*   ws_flaglist = (int*)(ws + WS_FLAGLST);
    uint4* ws_Bfrag    = (uint4*)(ws + WS_BFRAG);
    float* ws_cntpart  = ws + WS_CNTPART;
    float* ws_part     = ws + WS_PART;

    const int use_part = (ws_size >= WS_NEED_BYTES) ? 1 : 0;

    if (use_part) {
        hipMemsetAsync(ws + WS_DIFF, 0, 8, stream);          // diff + flagcnt only
    } else {
        hipMemsetAsync(d_ws, 0, (size_t)(WS_FLAGCNT + 1) * 4, stream);
    }

    prep_kernel<<<64, 256, 0, stream>>>(embed, ws_embedT, ws_ee, ws_Bfrag);
    dist_kernel<<<N_ROWS / 256, 256, 0, stream>>>(x, ws_Bfrag, ws_ee, ws_embedT,
                                                  out_q, out_ind, ws_idx, ws_diff,
                                                  ws_flagcnt, ws_flaglist);
    recheck_kernel<<<1024, 256, 0, stream>>>(x, embed, ws_embedT, ws_ee,
                                             ws_flagcnt, ws_flaglist,
                                             ws_idx, out_ind, out_q, ws_diff);
    scatter_kernel<<<NRANGE * 8, 1024, 0, stream>>>(
        ws_idx, x,
        use_part ? ws_part : ws_esum,
        use_part ? ws_cntpart : ws_cntf,
        use_part ? 0 : 1);
    finalize1<<<1, 1024, 0, stream>>>(cluster_size,
                                      use_part ? ws_cntpart : ws_cntf,
                                      use_part ? NRANGE : 1,
                                      ws_diff, out_diff, out_ncs, ws_n);
    finalize2<<<256, 256, 0, stream>>>(embed_avg,
                                       use_part ? ws_part : ws_esum,
                                       use_part ? NRANGE : 1,
                                       out_ncs, ws_n, out_nea, out_ne);
}

// Round 6
// 257.117 us; speedup vs baseline: 1.1875x; 1.0435x over previous
//
#include <hip/hip_runtime.h>

// VQ-VAE quantize + EMA update, MI355X.
// R14: launch count 7 -> 4 (others==166us constant across 5 rounds => suspect
//     fixed per-op overhead): recheck fused into dist (block-local flags,
//     batch-8 exact fp32 re-argmin), finalize1+2 fused, memset dropped (prep
//     zeroes ws_diff). dist: index-in-mantissa argmin keys
//     (key=(s&~0x3FF)|col, b2=med3, b1=min: 3 VALU/state, no index regs,
//     total order => deterministic lowest-col ties), TAU 0.02 -> 0.15 to
//     flag any key-perturbed pair (recheck makes it exact), 2-deep B
//     prefetch. Geometry reverted to R11's proven 1024x256 / 2rt (R13's
//     16-state config spilled: WRITE_SIZE 34->49MB).

#define N_ROWS 131072
#define DIM    64
#define NEMB   1024
#define NRANGE 32
#define KMASK  0xFFFFFC00u
#define TAUK   0.15f

static constexpr float DECAYF = 0.99f;
static constexpr float OMDF   = (float)(1.0 - 0.99);
static constexpr float EPSF   = 1e-5f;
static constexpr float NEPSF  = (float)(1024 * 1e-5);

typedef __attribute__((ext_vector_type(8))) short short8;
typedef __attribute__((ext_vector_type(4))) float f32x4;

static __device__ __forceinline__ unsigned short f2bf(float f) {
    unsigned int u = __builtin_bit_cast(unsigned int, f);
    unsigned int r = (u + 0x7FFFu + ((u >> 16) & 1u)) >> 16;   // RNE
    return (unsigned short)r;
}
static __device__ __forceinline__ float bf2f(unsigned short h) {
    unsigned int u = ((unsigned int)h) << 16;
    return __builtin_bit_cast(float, u);
}

// ws layout (float offsets)
#define WS_ESUM    0         // 65536 (atomic-fallback target)
#define WS_CNTF    65536     // 1024  (atomic-fallback counts)
#define WS_DIFF    66560     // 1
#define WS_FLAGCNT 66561     // 1 (unused R14)
#define WS_N       66562     // 1 (unused R14)
#define WS_EE      66564     // 1024
#define WS_EMBEDT  67588     // 65536 (16B aligned)
#define WS_IDX     133124    // 131072 (int)
#define WS_FLAGLST 264196    // 131072 (unused R14)
#define WS_BFRAG   395268    // 65536 floats = 256 KB (16B aligned)
#define WS_CNTPART 460804    // 32768 (NRANGE x 1024)
#define WS_PART    493572    // NRANGE x 65536 floats (16B aligned)
#define WS_NEED_BYTES ((size_t)(WS_PART + NRANGE * 65536) * 4)

// ---------------- prep: embedT, ee, hi/lo fragments of B' = -2*embed
__global__ void prep_kernel(const float* __restrict__ embed,
                            float* __restrict__ embedT,
                            float* __restrict__ ee,
                            uint4* __restrict__ BfragG,
                            float* __restrict__ ws_diff) {
    int tid = blockIdx.x * 256 + threadIdx.x;      // 0..16383
    if (tid == 0) ws_diff[0] = 0.f;
    for (int i = 0; i < 4; ++i) {
        int id = i * 16384 + tid;
        int d = id >> 10, e = id & 1023;
        embedT[e * 64 + d] = embed[id];
    }
    if (tid < NEMB) {
        float s = 0.f;
        for (int d = 0; d < DIM; ++d) {
            float v = embed[d * 1024 + tid];
            s = fmaf(v, v, s);
        }
        ee[tid] = s;
    }
    int fid  = tid >> 6;            // 0..255
    int lane = tid & 63;
    int hl = fid & 1, kt = (fid >> 1) & 1, ct = fid >> 2;
    int col = ct * 16 + (lane & 15);
    int k0  = kt * 32 + (lane >> 4) * 8;
    unsigned short u[8];
    #pragma unroll
    for (int j = 0; j < 8; ++j) {
        float v = -2.0f * embed[(k0 + j) * 1024 + col];
        unsigned short h = f2bf(v);
        if (hl) h = f2bf(v - bf2f(h));
        u[j] = h;
    }
    uint4 wv;
    wv.x = (unsigned)u[0] | ((unsigned)u[1] << 16);
    wv.y = (unsigned)u[2] | ((unsigned)u[3] << 16);
    wv.z = (unsigned)u[4] | ((unsigned)u[5] << 16);
    wv.w = (unsigned)u[6] | ((unsigned)u[7] << 16);
    BfragG[fid * 64 + lane] = wv;
}

// ---------------- dist: hi/lo MFMA + key-argmin + quantize + diff + recheck
__global__ __launch_bounds__(256) void dist_kernel(
        const float* __restrict__ x, const uint4* __restrict__ BfragG,
        const float* __restrict__ ee, const float* __restrict__ embed,
        const float* __restrict__ embedT,
        float* __restrict__ out_q, float* __restrict__ out_ind,
        int* __restrict__ ws_idx, float* __restrict__ ws_diff) {
    __shared__ float sEE[1024];           // 4 KB
    __shared__ int   sIdx[128];
    __shared__ float red[4];
    __shared__ int   sFlagCnt;
    __shared__ int   sFlagRows[128];
    __shared__ float sx[8][64];           // recheck stage
    __shared__ float sff[8];
    __shared__ float sbdw[8][4];
    __shared__ int   sbiw[8][4];
    __shared__ int   schg[8];

    const int t = threadIdx.x;
    const int w = t >> 6, lane = t & 63;
    const int quad = lane >> 4, wl = lane & 15;
    const int rbase = blockIdx.x * 128;

    short8 a_hi[2][2], a_lo[2][2];
    #pragma unroll
    for (int rt = 0; rt < 2; ++rt) {
        int row = rbase + w * 32 + rt * 16 + wl;
        #pragma unroll
        for (int kt = 0; kt < 2; ++kt) {
            const float* px = x + (size_t)row * 64 + kt * 32 + quad * 8;
            float4 v0 = *(const float4*)px;
            float4 v1 = *(const float4*)(px + 4);
            float vv[8] = {v0.x, v0.y, v0.z, v0.w, v1.x, v1.y, v1.z, v1.w};
            short8 ah, al;
            #pragma unroll
            for (int j = 0; j < 8; ++j) {
                unsigned short h = f2bf(vv[j]);
                ah[j] = (short)h;
                al[j] = (short)f2bf(vv[j] - bf2f(h));
            }
            a_hi[rt][kt] = ah; a_lo[rt][kt] = al;
        }
    }

    for (int i = t; i < 1024; i += 256) sEE[i] = ee[i];
    if (t == 0) sFlagCnt = 0;

    float b1[8], b2[8];
    #pragma unroll
    for (int s = 0; s < 8; ++s) { b1[s] = 3.4e38f; b2[s] = 3.4e38f; }

    const f32x4 zacc = {0.f, 0.f, 0.f, 0.f};

    __syncthreads();                      // sEE+sFlagCnt visible

    // main loop: 64 col-groups of 16 cols, staggered start, 2-deep prefetch.
    const int goff = blockIdx.x & 63;

#define GBODY(CB0, CB1, CB2, CB3, COLV)                                        \
    {                                                                          \
        short8 bh0 = __builtin_bit_cast(short8, CB0);                          \
        short8 bl0 = __builtin_bit_cast(short8, CB1);                          \
        short8 bh1 = __builtin_bit_cast(short8, CB2);                          \
        short8 bl1 = __builtin_bit_cast(short8, CB3);                          \
        float eec = sEE[COLV];                                                 \
        unsigned colu = (unsigned)(COLV);                                      \
        _Pragma("unroll")                                                      \
        for (int rt = 0; rt < 2; ++rt) {                                       \
            f32x4 c0 = __builtin_amdgcn_mfma_f32_16x16x32_bf16(a_lo[rt][0], bh0, zacc, 0, 0, 0); \
            f32x4 c1 = __builtin_amdgcn_mfma_f32_16x16x32_bf16(a_lo[rt][1], bh1, zacc, 0, 0, 0); \
            c0 = __builtin_amdgcn_mfma_f32_16x16x32_bf16(a_hi[rt][0], bl0, c0, 0, 0, 0); \
            c1 = __builtin_amdgcn_mfma_f32_16x16x32_bf16(a_hi[rt][1], bl1, c1, 0, 0, 0); \
            c0 = __builtin_amdgcn_mfma_f32_16x16x32_bf16(a_hi[rt][0], bh0, c0, 0, 0, 0); \
            c1 = __builtin_amdgcn_mfma_f32_16x16x32_bf16(a_hi[rt][1], bh1, c1, 0, 0, 0); \
            _Pragma("unroll")                                                  \
            for (int reg = 0; reg < 4; ++reg) {                                \
                float s = c0[reg] + c1[reg] + eec;                             \
                unsigned ku = (__builtin_bit_cast(unsigned, s) & KMASK) | colu;\
                float key = __builtin_bit_cast(float, ku);                     \
                int st = rt * 4 + reg;                                         \
                b2[st] = __builtin_amdgcn_fmed3f(key, b1[st], b2[st]);         \
                b1[st] = fminf(key, b1[st]);                                   \
            }                                                                  \
        }                                                                      \
    }

    {
        const uint4* bgl = BfragG + lane;
        int gA = goff, gB = (goff + 1) & 63;
        const uint4* pA = bgl + gA * 256;
        uint4 A0 = pA[0], A1 = pA[64], A2 = pA[128], A3 = pA[192];
        const uint4* pB = bgl + gB * 256;
        uint4 B0 = pB[0], B1 = pB[64], B2 = pB[128], B3 = pB[192];
        for (int it = 0; it < 64; it += 2) {
            int colA = ((goff + it) & 63) * 16 + wl;
            GBODY(A0, A1, A2, A3, colA);
            if (it + 2 < 64) {
                const uint4* p = bgl + (((goff + it + 2) & 63) * 256);
                A0 = p[0]; A1 = p[64]; A2 = p[128]; A3 = p[192];
            }
            int colB = ((goff + it + 1) & 63) * 16 + wl;
            GBODY(B0, B1, B2, B3, colB);
            if (it + 3 < 64) {
                const uint4* p = bgl + (((goff + it + 3) & 63) * 256);
                B0 = p[0]; B1 = p[64]; B2 = p[128]; B3 = p[192];
            }
        }
    }
#undef GBODY

    // cross-lane reduce over the 16 wl lanes; keys carry the index.
    for (int m = 1; m < 16; m <<= 1) {
        #pragma unroll
        for (int s = 0; s < 8; ++s) {
            float o1 = __shfl_xor(b1[s], m);
            float o2 = __shfl_xor(b2[s], m);
            float mx = fmaxf(b1[s], o1);
            b1[s] = fminf(b1[s], o1);
            b2[s] = fminf(fminf(b2[s], o2), mx);
        }
    }
    if (wl == 0) {
        #pragma unroll
        for (int s = 0; s < 8; ++s) {
            int rt = s >> 2, reg = s & 3;
            int rloc = w * 32 + rt * 16 + quad * 4 + reg;
            int row = rbase + rloc;
            unsigned kb = __builtin_bit_cast(unsigned, b1[s]);
            int col = (int)(kb & 1023u);
            sIdx[rloc] = col;
            ws_idx[row] = col;
            out_ind[row] = (float)col;
            float v1 = __builtin_bit_cast(float, kb & KMASK);
            float v2 = __builtin_bit_cast(float, __builtin_bit_cast(unsigned, b2[s]) & KMASK);
            if (v2 - v1 < TAUK) {
                int p = atomicAdd(&sFlagCnt, 1);
                sFlagRows[p] = rloc;               // p < 128 guaranteed
            }
        }
    }
    __syncthreads();

    // quantize + diff epilogue (old indices; flagged rows fixed below)
    {
        int r = t >> 1, hh = t & 1;
        int e = sIdx[r];
        const float4* et = (const float4*)(embedT + e * 64 + hh * 32);
        const float4* xr = (const float4*)(x + (size_t)(rbase + r) * 64 + hh * 32);
        float4*       qo = (float4*)(out_q + (size_t)(rbase + r) * 64 + hh * 32);
        float dsum = 0.f;
        #pragma unroll
        for (int v = 0; v < 8; ++v) {
            float4 q4 = et[v];
            float4 x4 = xr[v];
            float dx = q4.x - x4.x, dy = q4.y - x4.y, dz = q4.z - x4.z, dw = q4.w - x4.w;
            float4 o;
            o.x = x4.x + dx; o.y = x4.y + dy; o.z = x4.z + dz; o.w = x4.w + dw;
            qo[v] = o;
            dsum += dx * dx + dy * dy + dz * dz + dw * dw;
        }
        for (int o2 = 32; o2 > 0; o2 >>= 1) dsum += __shfl_down(dsum, o2);
        if (lane == 0) red[w] = dsum;
        __syncthreads();
        if (t == 0) atomicAdd(ws_diff, red[0] + red[1] + red[2] + red[3]);
    }

    // fused recheck: exact fp32 re-argmin for flagged rows, batches of 8.
    __syncthreads();                       // quantize stores drained
    int fcnt = sFlagCnt;
    for (int base = 0; base < fcnt; base += 8) {
        int nr = fcnt - base; if (nr > 8) nr = 8;
        __syncthreads();                   // sx reuse guard
        for (int l = t; l < nr * 64; l += 256) {
            int rl = sFlagRows[base + (l >> 6)];
            sx[l >> 6][l & 63] = x[(size_t)(rbase + rl) * 64 + (l & 63)];
        }
        __syncthreads();
        if (t < nr) {
            float ff = 0.f;
            for (int k = 0; k < 64; ++k) ff = fmaf(sx[t][k], sx[t][k], ff);
            sff[t] = ff;
        }
        float acc[8][4];
        #pragma unroll
        for (int r = 0; r < 8; ++r)
            #pragma unroll
            for (int j = 0; j < 4; ++j) acc[r][j] = 0.f;
        int c0i = t * 4;
        for (int k = 0; k < 64; ++k) {
            float4 e4 = *(const float4*)(embed + k * 1024 + c0i);
            #pragma unroll
            for (int r = 0; r < 8; ++r) {
                float xk = sx[r][k];
                acc[r][0] = fmaf(xk, e4.x, acc[r][0]);
                acc[r][1] = fmaf(xk, e4.y, acc[r][1]);
                acc[r][2] = fmaf(xk, e4.z, acc[r][2]);
                acc[r][3] = fmaf(xk, e4.w, acc[r][3]);
            }
        }
        __syncthreads();                   // sff visible
        #pragma unroll
        for (int r = 0; r < 8; ++r) {
            if (r < nr) {
                float ff = sff[r];
                float bd = 3.4e38f; int bi = 0;
                #pragma unroll
                for (int j = 0; j < 4; ++j) {
                    float d = (ff - 2.f * acc[r][j]) + sEE[c0i + j];
                    if (d < bd) { bd = d; bi = c0i + j; }
                }
                for (int m = 32; m > 0; m >>= 1) {
                    float od = __shfl_xor(bd, m);
                    int   oi = __shfl_xor(bi, m);
                    if (od < bd || (od == bd && oi < bi)) { bd = od; bi = oi; }
                }
                if (lane == 0) { sbdw[r][w] = bd; sbiw[r][w] = bi; }
            }
        }
        __syncthreads();
        if (t < nr) {
            float bd = sbdw[t][0]; int bi = sbiw[t][0];
            #pragma unroll
            for (int k2 = 1; k2 < 4; ++k2) {
                float od = sbdw[t][k2]; int oi = sbiw[t][k2];
                if (od < bd || (od == bd && oi < bi)) { bd = od; bi = oi; }
            }
            int rl = sFlagRows[base + t];
            int oi_ = sIdx[rl];
            schg[t] = (bi != oi_) ? bi : -1;
            if (bi != oi_) {
                ws_idx[rbase + rl] = bi;
                out_ind[rbase + rl] = (float)bi;
            }
        }
        __syncthreads();
        for (int r = w; r < nr; r += 4) {
            int ni = schg[r];
            if (ni >= 0) {
                int rl = sFlagRows[base + r];
                int row = rbase + rl;
                int oi_ = sIdx[rl];
                float xv = sx[r][lane];
                float dn   = embedT[ni * 64 + lane] - xv;
                float dold = embedT[oi_ * 64 + lane] - xv;
                out_q[(size_t)row * 64 + lane] = xv + dn;
                float delta = dn * dn - dold * dold;
                for (int o = 32; o > 0; o >>= 1) delta += __shfl_down(delta, o);
                if (lane == 0) atomicAdd(ws_diff, delta);
            }
        }
    }
}

// ---------------- scatter: 32 ranges x 8 dim-octants (R13 form, unchanged)
__global__ __launch_bounds__(1024) void scatter_kernel(
        const int* __restrict__ idx, const float* __restrict__ x,
        float* __restrict__ part_or_esum, float* __restrict__ cntp_or_cntf,
        int use_atomic) {
    __shared__ float shist[8192];         // [1024 codes][8 dims] = 32 KB
    __shared__ float scnt[1024];
    const int t = threadIdx.x;
    const int bid = blockIdx.x;
    const int oct = (bid >> 3) & 7;
    const int rb  = (bid & 7) | ((bid >> 6) << 3);
    const int sid = rb * 8 + oct;
    const int w = t >> 6, lane = t & 63;
    const int g = lane >> 3, d = lane & 7;

    for (int i = t; i < 8192; i += 1024) shist[i] = 0.f;
    if (oct == 0) { if (t < 1024) scnt[t] = 0.f; }
    __syncthreads();

    const int row0 = rb * 4096 + w * 256;
    int rcur = row0 + g;
    int e_n = idx[rcur];
    float x_n = x[(size_t)rcur * 64 + oct * 8 + d];
    for (int it = 0; it < 32; ++it) {
        int e = e_n; float xv = x_n;
        int rnext = rcur + 8;
        if (it < 31) {
            e_n = idx[rnext];
            x_n = x[(size_t)rnext * 64 + oct * 8 + d];
        }
        rcur = rnext;
        atomicAdd(&shist[e * 8 + d], xv);
        if (oct == 0 && d == 0) atomicAdd(&scnt[e], 1.0f);
    }
    __syncthreads();

    if (!use_atomic) {
        float* dst = part_or_esum + (size_t)sid * 8192;
        for (int out = t; out < 8192; out += 1024)
            dst[out] = shist[(out & 1023) * 8 + (out >> 10)];
        if (oct == 0) {
            float* cdst = cntp_or_cntf + rb * 1024;
            if (t < 1024) cdst[t] = scnt[t];
        }
    } else {
        for (int out = t; out < 8192; out += 1024) {
            float v = shist[(out & 1023) * 8 + (out >> 10)];
            if (v != 0.f)
                atomicAdd(&part_or_esum[(oct * 8 + (out >> 10)) * 1024 + (out & 1023)], v);
        }
        if (oct == 0) {
            if (t < 1024) {
                float c = scnt[t];
                if (c != 0.f) atomicAdd(&cntp_or_cntf[t], c);
            }
        }
    }
}

// ---------------- finalizeF: fused finalize1+finalize2 (64 blocks x 1024)
__global__ __launch_bounds__(1024) void finalizeF(
        const float* __restrict__ cluster_size, const float* __restrict__ cntp,
        const float* __restrict__ part, int nrb,
        const float* __restrict__ ws_diff, const float* __restrict__ embed_avg,
        float* __restrict__ out_diff, float* __restrict__ out_ncs,
        float* __restrict__ out_nea, float* __restrict__ out_ne) {
    __shared__ float sred[16];
    __shared__ float sn;
    const int tid = threadIdx.x;
    const int b = blockIdx.x;
    float c = 0.f;
    for (int k = 0; k < nrb; ++k) c += cntp[k * 1024 + tid];
    float ncs = DECAYF * cluster_size[tid] + OMDF * c;
    float v = ncs;
    for (int o = 32; o > 0; o >>= 1) v += __shfl_down(v, o);
    if ((tid & 63) == 0) sred[tid >> 6] = v;
    __syncthreads();
    if (tid == 0) {
        float n = 0.f;
        for (int i = 0; i < 16; ++i) n += sred[i];
        sn = n;
        if (b == 0) out_diff[0] = ws_diff[0] * (1.0f / 8388608.0f);
    }
    __syncthreads();
    float n = sn;
    if (b == 0) out_ncs[tid] = ncs;
    int j = b * 1024 + tid;                       // dim = b, code = tid
    float es = 0.f;
    for (int k = 0; k < nrb; ++k) es += part[(size_t)k * 65536 + j];
    float nea = DECAYF * embed_avg[j] + OMDF * es;
    out_nea[j] = nea;
    float cs = (ncs + EPSF) / (n + NEPSF) * n;
    out_ne[j] = nea / cs;
}

extern "C" void kernel_launch(void* const* d_in, const int* in_sizes, int n_in,
                              void* d_out, int out_size, void* d_ws, size_t ws_size,
                              hipStream_t stream) {
    const float* x            = (const float*)d_in[0];
    const float* embed        = (const float*)d_in[1];
    const float* cluster_size = (const float*)d_in[2];
    const float* embed_avg    = (const float*)d_in[3];

    float* out = (float*)d_out;
    float* out_q    = out;                       // 8388608
    float* out_diff = out + 8388608;             // 1
    float* out_ind  = out + 8388609;             // 131072
    float* out_ncs  = out + 8519681;             // 1024
    float* out_nea  = out + 8520705;             // 65536
    float* out_ne   = out + 8586241;             // 65536

    float* ws = (float*)d_ws;
    float* ws_esum     = ws + WS_ESUM;
    float* ws_cntf     = ws + WS_CNTF;
    float* ws_diff     = ws + WS_DIFF;
    float* ws_ee       = ws + WS_EE;
    float* ws_embedT   = ws + WS_EMBEDT;
    int*   ws_idx      = (int*)(ws + WS_IDX);
    uint4* ws_Bfrag    = (uint4*)(ws + WS_BFRAG);
    float* ws_cntpart  = ws + WS_CNTPART;
    float* ws_part     = ws + WS_PART;

    const int use_part = (ws_size >= WS_NEED_BYTES) ? 1 : 0;

    if (!use_part) {
        // atomic fallback needs zeroed esum/cntf (+diff)
        hipMemsetAsync(d_ws, 0, (size_t)(WS_FLAGCNT + 1) * 4, stream);
    }

    prep_kernel<<<64, 256, 0, stream>>>(embed, ws_embedT, ws_ee, ws_Bfrag, ws_diff);
    dist_kernel<<<N_ROWS / 128, 256, 0, stream>>>(x, ws_Bfrag, ws_ee, embed,
                                                  ws_embedT, out_q, out_ind,
                                                  ws_idx, ws_diff);
    scatter_kernel<<<NRANGE * 8, 1024, 0, stream>>>(
        ws_idx, x,
        use_part ? ws_part : ws_esum,
        use_part ? ws_cntpart : ws_cntf,
        use_part ? 0 : 1);
    finalizeF<<<64, 1024, 0, stream>>>(cluster_size,
                                       use_part ? ws_cntpart : ws_cntf,
                                       use_part ? ws_part : ws_esum,
                                       use_part ? NRANGE : 1,
                                       ws_diff, embed_avg,
                                       out_diff, out_ncs, out_nea, out_ne);
}

// Round 7
// 254.375 us; speedup vs baseline: 1.2003x; 1.0108x over previous
//
#include <hip/hip_runtime.h>

// VQ-VAE quantize + EMA update, MI355X.
// R15 == R14 with ONE change: argmin keys are ROUNDED to 2^-10-mantissa
//     (ku = (u+0x200)&~0x3FF | col) instead of truncated, and TAUK 0.15 ->
//     0.05. R14 post-mortem: total 268->257 (op-fusion overhead theory
//     confirmed, ~19us/op) but dist 103.6->147 because TAUK=0.15 flagged
//     ~10% of rows -> ~2 full-embed recheck batches/block (~40us tail).
//     Error budget: mfma err ~0.01 + 2x rounding err (<=0.0078 @ s<256)
//     => 0.05 is safe with margin; flag rate drops ~3x.

#define N_ROWS 131072
#define DIM    64
#define NEMB   1024
#define NRANGE 32
#define KMASK  0xFFFFFC00u
#define TAUK   0.05f

static constexpr float DECAYF = 0.99f;
static constexpr float OMDF   = (float)(1.0 - 0.99);
static constexpr float EPSF   = 1e-5f;
static constexpr float NEPSF  = (float)(1024 * 1e-5);

typedef __attribute__((ext_vector_type(8))) short short8;
typedef __attribute__((ext_vector_type(4))) float f32x4;

static __device__ __forceinline__ unsigned short f2bf(float f) {
    unsigned int u = __builtin_bit_cast(unsigned int, f);
    unsigned int r = (u + 0x7FFFu + ((u >> 16) & 1u)) >> 16;   // RNE
    return (unsigned short)r;
}
static __device__ __forceinline__ float bf2f(unsigned short h) {
    unsigned int u = ((unsigned int)h) << 16;
    return __builtin_bit_cast(float, u);
}

// ws layout (float offsets)
#define WS_ESUM    0         // 65536 (atomic-fallback target)
#define WS_CNTF    65536     // 1024  (atomic-fallback counts)
#define WS_DIFF    66560     // 1
#define WS_FLAGCNT 66561     // 1 (unused R15)
#define WS_N       66562     // 1 (unused R15)
#define WS_EE      66564     // 1024
#define WS_EMBEDT  67588     // 65536 (16B aligned)
#define WS_IDX     133124    // 131072 (int)
#define WS_FLAGLST 264196    // 131072 (unused R15)
#define WS_BFRAG   395268    // 65536 floats = 256 KB (16B aligned)
#define WS_CNTPART 460804    // 32768 (NRANGE x 1024)
#define WS_PART    493572    // NRANGE x 65536 floats (16B aligned)
#define WS_NEED_BYTES ((size_t)(WS_PART + NRANGE * 65536) * 4)

// ---------------- prep: embedT, ee, hi/lo fragments of B' = -2*embed
__global__ void prep_kernel(const float* __restrict__ embed,
                            float* __restrict__ embedT,
                            float* __restrict__ ee,
                            uint4* __restrict__ BfragG,
                            float* __restrict__ ws_diff) {
    int tid = blockIdx.x * 256 + threadIdx.x;      // 0..16383
    if (tid == 0) ws_diff[0] = 0.f;
    for (int i = 0; i < 4; ++i) {
        int id = i * 16384 + tid;
        int d = id >> 10, e = id & 1023;
        embedT[e * 64 + d] = embed[id];
    }
    if (tid < NEMB) {
        float s = 0.f;
        for (int d = 0; d < DIM; ++d) {
            float v = embed[d * 1024 + tid];
            s = fmaf(v, v, s);
        }
        ee[tid] = s;
    }
    int fid  = tid >> 6;            // 0..255
    int lane = tid & 63;
    int hl = fid & 1, kt = (fid >> 1) & 1, ct = fid >> 2;
    int col = ct * 16 + (lane & 15);
    int k0  = kt * 32 + (lane >> 4) * 8;
    unsigned short u[8];
    #pragma unroll
    for (int j = 0; j < 8; ++j) {
        float v = -2.0f * embed[(k0 + j) * 1024 + col];
        unsigned short h = f2bf(v);
        if (hl) h = f2bf(v - bf2f(h));
        u[j] = h;
    }
    uint4 wv;
    wv.x = (unsigned)u[0] | ((unsigned)u[1] << 16);
    wv.y = (unsigned)u[2] | ((unsigned)u[3] << 16);
    wv.z = (unsigned)u[4] | ((unsigned)u[5] << 16);
    wv.w = (unsigned)u[6] | ((unsigned)u[7] << 16);
    BfragG[fid * 64 + lane] = wv;
}

// ---------------- dist: hi/lo MFMA + key-argmin + quantize + diff + recheck
__global__ __launch_bounds__(256) void dist_kernel(
        const float* __restrict__ x, const uint4* __restrict__ BfragG,
        const float* __restrict__ ee, const float* __restrict__ embed,
        const float* __restrict__ embedT,
        float* __restrict__ out_q, float* __restrict__ out_ind,
        int* __restrict__ ws_idx, float* __restrict__ ws_diff) {
    __shared__ float sEE[1024];           // 4 KB
    __shared__ int   sIdx[128];
    __shared__ float red[4];
    __shared__ int   sFlagCnt;
    __shared__ int   sFlagRows[128];
    __shared__ float sx[8][64];           // recheck stage
    __shared__ float sff[8];
    __shared__ float sbdw[8][4];
    __shared__ int   sbiw[8][4];
    __shared__ int   schg[8];

    const int t = threadIdx.x;
    const int w = t >> 6, lane = t & 63;
    const int quad = lane >> 4, wl = lane & 15;
    const int rbase = blockIdx.x * 128;

    short8 a_hi[2][2], a_lo[2][2];
    #pragma unroll
    for (int rt = 0; rt < 2; ++rt) {
        int row = rbase + w * 32 + rt * 16 + wl;
        #pragma unroll
        for (int kt = 0; kt < 2; ++kt) {
            const float* px = x + (size_t)row * 64 + kt * 32 + quad * 8;
            float4 v0 = *(const float4*)px;
            float4 v1 = *(const float4*)(px + 4);
            float vv[8] = {v0.x, v0.y, v0.z, v0.w, v1.x, v1.y, v1.z, v1.w};
            short8 ah, al;
            #pragma unroll
            for (int j = 0; j < 8; ++j) {
                unsigned short h = f2bf(vv[j]);
                ah[j] = (short)h;
                al[j] = (short)f2bf(vv[j] - bf2f(h));
            }
            a_hi[rt][kt] = ah; a_lo[rt][kt] = al;
        }
    }

    for (int i = t; i < 1024; i += 256) sEE[i] = ee[i];
    if (t == 0) sFlagCnt = 0;

    float b1[8], b2[8];
    #pragma unroll
    for (int s = 0; s < 8; ++s) { b1[s] = 3.4e38f; b2[s] = 3.4e38f; }

    const f32x4 zacc = {0.f, 0.f, 0.f, 0.f};

    __syncthreads();                      // sEE+sFlagCnt visible

    // main loop: 64 col-groups of 16 cols, staggered start, 2-deep prefetch.
    const int goff = blockIdx.x & 63;

#define GBODY(CB0, CB1, CB2, CB3, COLV)                                        \
    {                                                                          \
        short8 bh0 = __builtin_bit_cast(short8, CB0);                          \
        short8 bl0 = __builtin_bit_cast(short8, CB1);                          \
        short8 bh1 = __builtin_bit_cast(short8, CB2);                          \
        short8 bl1 = __builtin_bit_cast(short8, CB3);                          \
        float eec = sEE[COLV];                                                 \
        unsigned colu = (unsigned)(COLV);                                      \
        _Pragma("unroll")                                                      \
        for (int rt = 0; rt < 2; ++rt) {                                       \
            f32x4 c0 = __builtin_amdgcn_mfma_f32_16x16x32_bf16(a_lo[rt][0], bh0, zacc, 0, 0, 0); \
            f32x4 c1 = __builtin_amdgcn_mfma_f32_16x16x32_bf16(a_lo[rt][1], bh1, zacc, 0, 0, 0); \
            c0 = __builtin_amdgcn_mfma_f32_16x16x32_bf16(a_hi[rt][0], bl0, c0, 0, 0, 0); \
            c1 = __builtin_amdgcn_mfma_f32_16x16x32_bf16(a_hi[rt][1], bl1, c1, 0, 0, 0); \
            c0 = __builtin_amdgcn_mfma_f32_16x16x32_bf16(a_hi[rt][0], bh0, c0, 0, 0, 0); \
            c1 = __builtin_amdgcn_mfma_f32_16x16x32_bf16(a_hi[rt][1], bh1, c1, 0, 0, 0); \
            _Pragma("unroll")                                                  \
            for (int reg = 0; reg < 4; ++reg) {                                \
                float s = c0[reg] + c1[reg] + eec;                             \
                unsigned ku = ((__builtin_bit_cast(unsigned, s) + 0x200u) & KMASK) | colu; \
                float key = __builtin_bit_cast(float, ku);                     \
                int st = rt * 4 + reg;                                         \
                b2[st] = __builtin_amdgcn_fmed3f(key, b1[st], b2[st]);         \
                b1[st] = fminf(key, b1[st]);                                   \
            }                                                                  \
        }                                                                      \
    }

    {
        const uint4* bgl = BfragG + lane;
        int gA = goff, gB = (goff + 1) & 63;
        const uint4* pA = bgl + gA * 256;
        uint4 A0 = pA[0], A1 = pA[64], A2 = pA[128], A3 = pA[192];
        const uint4* pB = bgl + gB * 256;
        uint4 B0 = pB[0], B1 = pB[64], B2 = pB[128], B3 = pB[192];
        for (int it = 0; it < 64; it += 2) {
            int colA = ((goff + it) & 63) * 16 + wl;
            GBODY(A0, A1, A2, A3, colA);
            if (it + 2 < 64) {
                const uint4* p = bgl + (((goff + it + 2) & 63) * 256);
                A0 = p[0]; A1 = p[64]; A2 = p[128]; A3 = p[192];
            }
            int colB = ((goff + it + 1) & 63) * 16 + wl;
            GBODY(B0, B1, B2, B3, colB);
            if (it + 3 < 64) {
                const uint4* p = bgl + (((goff + it + 3) & 63) * 256);
                B0 = p[0]; B1 = p[64]; B2 = p[128]; B3 = p[192];
            }
        }
    }
#undef GBODY

    // cross-lane reduce over the 16 wl lanes; keys carry the index.
    for (int m = 1; m < 16; m <<= 1) {
        #pragma unroll
        for (int s = 0; s < 8; ++s) {
            float o1 = __shfl_xor(b1[s], m);
            float o2 = __shfl_xor(b2[s], m);
            float mx = fmaxf(b1[s], o1);
            b1[s] = fminf(b1[s], o1);
            b2[s] = fminf(fminf(b2[s], o2), mx);
        }
    }
    if (wl == 0) {
        #pragma unroll
        for (int s = 0; s < 8; ++s) {
            int rt = s >> 2, reg = s & 3;
            int rloc = w * 32 + rt * 16 + quad * 4 + reg;
            int row = rbase + rloc;
            unsigned kb = __builtin_bit_cast(unsigned, b1[s]);
            int col = (int)(kb & 1023u);
            sIdx[rloc] = col;
            ws_idx[row] = col;
            out_ind[row] = (float)col;
            float v1 = __builtin_bit_cast(float, kb & KMASK);
            float v2 = __builtin_bit_cast(float, __builtin_bit_cast(unsigned, b2[s]) & KMASK);
            if (v2 - v1 < TAUK) {
                int p = atomicAdd(&sFlagCnt, 1);
                sFlagRows[p] = rloc;               // p < 128 guaranteed
            }
        }
    }
    __syncthreads();

    // quantize + diff epilogue (old indices; flagged rows fixed below)
    {
        int r = t >> 1, hh = t & 1;
        int e = sIdx[r];
        const float4* et = (const float4*)(embedT + e * 64 + hh * 32);
        const float4* xr = (const float4*)(x + (size_t)(rbase + r) * 64 + hh * 32);
        float4*       qo = (float4*)(out_q + (size_t)(rbase + r) * 64 + hh * 32);
        float dsum = 0.f;
        #pragma unroll
        for (int v = 0; v < 8; ++v) {
            float4 q4 = et[v];
            float4 x4 = xr[v];
            float dx = q4.x - x4.x, dy = q4.y - x4.y, dz = q4.z - x4.z, dw = q4.w - x4.w;
            float4 o;
            o.x = x4.x + dx; o.y = x4.y + dy; o.z = x4.z + dz; o.w = x4.w + dw;
            qo[v] = o;
            dsum += dx * dx + dy * dy + dz * dz + dw * dw;
        }
        for (int o2 = 32; o2 > 0; o2 >>= 1) dsum += __shfl_down(dsum, o2);
        if (lane == 0) red[w] = dsum;
        __syncthreads();
        if (t == 0) atomicAdd(ws_diff, red[0] + red[1] + red[2] + red[3]);
    }

    // fused recheck: exact fp32 re-argmin for flagged rows, batches of 8.
    __syncthreads();                       // quantize stores drained
    int fcnt = sFlagCnt;
    for (int base = 0; base < fcnt; base += 8) {
        int nr = fcnt - base; if (nr > 8) nr = 8;
        __syncthreads();                   // sx reuse guard
        for (int l = t; l < nr * 64; l += 256) {
            int rl = sFlagRows[base + (l >> 6)];
            sx[l >> 6][l & 63] = x[(size_t)(rbase + rl) * 64 + (l & 63)];
        }
        __syncthreads();
        if (t < nr) {
            float ff = 0.f;
            for (int k = 0; k < 64; ++k) ff = fmaf(sx[t][k], sx[t][k], ff);
            sff[t] = ff;
        }
        float acc[8][4];
        #pragma unroll
        for (int r = 0; r < 8; ++r)
            #pragma unroll
            for (int j = 0; j < 4; ++j) acc[r][j] = 0.f;
        int c0i = t * 4;
        for (int k = 0; k < 64; ++k) {
            float4 e4 = *(const float4*)(embed + k * 1024 + c0i);
            #pragma unroll
            for (int r = 0; r < 8; ++r) {
                float xk = sx[r][k];
                acc[r][0] = fmaf(xk, e4.x, acc[r][0]);
                acc[r][1] = fmaf(xk, e4.y, acc[r][1]);
                acc[r][2] = fmaf(xk, e4.z, acc[r][2]);
                acc[r][3] = fmaf(xk, e4.w, acc[r][3]);
            }
        }
        __syncthreads();                   // sff visible
        #pragma unroll
        for (int r = 0; r < 8; ++r) {
            if (r < nr) {
                float ff = sff[r];
                float bd = 3.4e38f; int bi = 0;
                #pragma unroll
                for (int j = 0; j < 4; ++j) {
                    float d = (ff - 2.f * acc[r][j]) + sEE[c0i + j];
                    if (d < bd) { bd = d; bi = c0i + j; }
                }
                for (int m = 32; m > 0; m >>= 1) {
                    float od = __shfl_xor(bd, m);
                    int   oi = __shfl_xor(bi, m);
                    if (od < bd || (od == bd && oi < bi)) { bd = od; bi = oi; }
                }
                if (lane == 0) { sbdw[r][w] = bd; sbiw[r][w] = bi; }
            }
        }
        __syncthreads();
        if (t < nr) {
            float bd = sbdw[t][0]; int bi = sbiw[t][0];
            #pragma unroll
            for (int k2 = 1; k2 < 4; ++k2) {
                float od = sbdw[t][k2]; int oi = sbiw[t][k2];
                if (od < bd || (od == bd && oi < bi)) { bd = od; bi = oi; }
            }
            int rl = sFlagRows[base + t];
            int oi_ = sIdx[rl];
            schg[t] = (bi != oi_) ? bi : -1;
            if (bi != oi_) {
                ws_idx[rbase + rl] = bi;
                out_ind[rbase + rl] = (float)bi;
            }
        }
        __syncthreads();
        for (int r = w; r < nr; r += 4) {
            int ni = schg[r];
            if (ni >= 0) {
                int rl = sFlagRows[base + r];
                int row = rbase + rl;
                int oi_ = sIdx[rl];
                float xv = sx[r][lane];
                float dn   = embedT[ni * 64 + lane] - xv;
                float dold = embedT[oi_ * 64 + lane] - xv;
                out_q[(size_t)row * 64 + lane] = xv + dn;
                float delta = dn * dn - dold * dold;
                for (int o = 32; o > 0; o >>= 1) delta += __shfl_down(delta, o);
                if (lane == 0) atomicAdd(ws_diff, delta);
            }
        }
    }
}

// ---------------- scatter: 32 ranges x 8 dim-octants (unchanged)
__global__ __launch_bounds__(1024) void scatter_kernel(
        const int* __restrict__ idx, const float* __restrict__ x,
        float* __restrict__ part_or_esum, float* __restrict__ cntp_or_cntf,
        int use_atomic) {
    __shared__ float shist[8192];         // [1024 codes][8 dims] = 32 KB
    __shared__ float scnt[1024];
    const int t = threadIdx.x;
    const int bid = blockIdx.x;
    const int oct = (bid >> 3) & 7;
    const int rb  = (bid & 7) | ((bid >> 6) << 3);
    const int sid = rb * 8 + oct;
    const int w = t >> 6, lane = t & 63;
    const int g = lane >> 3, d = lane & 7;

    for (int i = t; i < 8192; i += 1024) shist[i] = 0.f;
    if (oct == 0) { if (t < 1024) scnt[t] = 0.f; }
    __syncthreads();

    const int row0 = rb * 4096 + w * 256;
    int rcur = row0 + g;
    int e_n = idx[rcur];
    float x_n = x[(size_t)rcur * 64 + oct * 8 + d];
    for (int it = 0; it < 32; ++it) {
        int e = e_n; float xv = x_n;
        int rnext = rcur + 8;
        if (it < 31) {
            e_n = idx[rnext];
            x_n = x[(size_t)rnext * 64 + oct * 8 + d];
        }
        rcur = rnext;
        atomicAdd(&shist[e * 8 + d], xv);
        if (oct == 0 && d == 0) atomicAdd(&scnt[e], 1.0f);
    }
    __syncthreads();

    if (!use_atomic) {
        float* dst = part_or_esum + (size_t)sid * 8192;
        for (int out = t; out < 8192; out += 1024)
            dst[out] = shist[(out & 1023) * 8 + (out >> 10)];
        if (oct == 0) {
            float* cdst = cntp_or_cntf + rb * 1024;
            if (t < 1024) cdst[t] = scnt[t];
        }
    } else {
        for (int out = t; out < 8192; out += 1024) {
            float v = shist[(out & 1023) * 8 + (out >> 10)];
            if (v != 0.f)
                atomicAdd(&part_or_esum[(oct * 8 + (out >> 10)) * 1024 + (out & 1023)], v);
        }
        if (oct == 0) {
            if (t < 1024) {
                float c = scnt[t];
                if (c != 0.f) atomicAdd(&cntp_or_cntf[t], c);
            }
        }
    }
}

// ---------------- finalizeF: fused finalize1+finalize2 (64 blocks x 1024)
__global__ __launch_bounds__(1024) void finalizeF(
        const float* __restrict__ cluster_size, const float* __restrict__ cntp,
        const float* __restrict__ part, int nrb,
        const float* __restrict__ ws_diff, const float* __restrict__ embed_avg,
        float* __restrict__ out_diff, float* __restrict__ out_ncs,
        float* __restrict__ out_nea, float* __restrict__ out_ne) {
    __shared__ float sred[16];
    __shared__ float sn;
    const int tid = threadIdx.x;
    const int b = blockIdx.x;
    float c = 0.f;
    for (int k = 0; k < nrb; ++k) c += cntp[k * 1024 + tid];
    float ncs = DECAYF * cluster_size[tid] + OMDF * c;
    float v = ncs;
    for (int o = 32; o > 0; o >>= 1) v += __shfl_down(v, o);
    if ((tid & 63) == 0) sred[tid >> 6] = v;
    __syncthreads();
    if (tid == 0) {
        float n = 0.f;
        for (int i = 0; i < 16; ++i) n += sred[i];
        sn = n;
        if (b == 0) out_diff[0] = ws_diff[0] * (1.0f / 8388608.0f);
    }
    __syncthreads();
    float n = sn;
    if (b == 0) out_ncs[tid] = ncs;
    int j = b * 1024 + tid;                       // dim = b, code = tid
    float es = 0.f;
    for (int k = 0; k < nrb; ++k) es += part[(size_t)k * 65536 + j];
    float nea = DECAYF * embed_avg[j] + OMDF * es;
    out_nea[j] = nea;
    float cs = (ncs + EPSF) / (n + NEPSF) * n;
    out_ne[j] = nea / cs;
}

extern "C" void kernel_launch(void* const* d_in, const int* in_sizes, int n_in,
                              void* d_out, int out_size, void* d_ws, size_t ws_size,
                              hipStream_t stream) {
    const float* x            = (const float*)d_in[0];
    const float* embed        = (const float*)d_in[1];
    const float* cluster_size = (const float*)d_in[2];
    const float* embed_avg    = (const float*)d_in[3];

    float* out = (float*)d_out;
    float* out_q    = out;                       // 8388608
    float* out_diff = out + 8388608;             // 1
    float* out_ind  = out + 8388609;             // 131072
    float* out_ncs  = out + 8519681;             // 1024
    float* out_nea  = out + 8520705;             // 65536
    float* out_ne   = out + 8586241;             // 65536

    float* ws = (float*)d_ws;
    float* ws_esum     = ws + WS_ESUM;
    float* ws_cntf     = ws + WS_CNTF;
    float* ws_diff     = ws + WS_DIFF;
    float* ws_ee       = ws + WS_EE;
    float* ws_embedT   = ws + WS_EMBEDT;
    int*   ws_idx      = (int*)(ws + WS_IDX);
    uint4* ws_Bfrag    = (uint4*)(ws + WS_BFRAG);
    float* ws_cntpart  = ws + WS_CNTPART;
    float* ws_part     = ws + WS_PART;

    const int use_part = (ws_size >= WS_NEED_BYTES) ? 1 : 0;

    if (!use_part) {
        // atomic fallback needs zeroed esum/cntf (+diff)
        hipMemsetAsync(d_ws, 0, (size_t)(WS_FLAGCNT + 1) * 4, stream);
    }

    prep_kernel<<<64, 256, 0, stream>>>(embed, ws_embedT, ws_ee, ws_Bfrag, ws_diff);
    dist_kernel<<<N_ROWS / 128, 256, 0, stream>>>(x, ws_Bfrag, ws_ee, embed,
                                                  ws_embedT, out_q, out_ind,
                                                  ws_idx, ws_diff);
    scatter_kernel<<<NRANGE * 8, 1024, 0, stream>>>(
        ws_idx, x,
        use_part ? ws_part : ws_esum,
        use_part ? ws_cntpart : ws_cntf,
        use_part ? 0 : 1);
    finalizeF<<<64, 1024, 0, stream>>>(cluster_size,
                                       use_part ? ws_cntpart : ws_cntf,
                                       use_part ? ws_part : ws_esum,
                                       use_part ? NRANGE : 1,
                                       ws_diff, embed_avg,
                                       out_diff, out_ncs, out_nea, out_ne);
}

// Round 10
// 247.923 us; speedup vs baseline: 1.2315x; 1.0260x over previous
//
#include <hip/hip_runtime.h>

// VQ-VAE quantize + EMA update, MI355X.
// R18 == R17 verbatim resubmit. R16+R17 both hit "container failed twice";
//     R17 already removed the coop-launch suspect, and a line audit of the
//     new dist loop shows no OOB/hang path (prefetch guards keep max index
//     at 16383/16384; flags <=128/block; uniform barriers). Error string
//     matches Round 2's proven infra flake (same kernel passed on resubmit).
//     Third consecutive failure would indict this source file itself.
// R17: R16's dist (addressing-thinned main loop: linear walk, imm-offset
//     loads, register col, 4-deep prefetch) + R15's PLAIN scatter/finalizeF.

#define N_ROWS 131072
#define DIM    64
#define NEMB   1024
#define NRANGE 32
#define KMASK  0xFFFFFC00u
#define TAUK   0.05f

static constexpr float DECAYF = 0.99f;
static constexpr float OMDF   = (float)(1.0 - 0.99);
static constexpr float EPSF   = 1e-5f;
static constexpr float NEPSF  = (float)(1024 * 1e-5);

typedef __attribute__((ext_vector_type(8))) short short8;
typedef __attribute__((ext_vector_type(4))) float f32x4;

static __device__ __forceinline__ unsigned short f2bf(float f) {
    unsigned int u = __builtin_bit_cast(unsigned int, f);
    unsigned int r = (u + 0x7FFFu + ((u >> 16) & 1u)) >> 16;   // RNE
    return (unsigned short)r;
}
static __device__ __forceinline__ float bf2f(unsigned short h) {
    unsigned int u = ((unsigned int)h) << 16;
    return __builtin_bit_cast(float, u);
}

// ws layout (float offsets)
#define WS_ESUM    0         // 65536 (atomic-fallback target)
#define WS_CNTF    65536     // 1024  (atomic-fallback counts)
#define WS_DIFF    66560     // 1
#define WS_FLAGCNT 66561     // 1 (unused)
#define WS_N       66562     // 1 (unused)
#define WS_EE      66564     // 1024
#define WS_EMBEDT  67588     // 65536 (16B aligned)
#define WS_IDX     133124    // 131072 (int)
#define WS_FLAGLST 264196    // 131072 (unused)
#define WS_BFRAG   395268    // 65536 floats = 256 KB (16B aligned)
#define WS_CNTPART 460804    // 32768 (NRANGE x 1024)
#define WS_PART    493572    // NRANGE x 65536 floats (16B aligned)
#define WS_NEED_BYTES ((size_t)(WS_PART + NRANGE * 65536) * 4)

// ---------------- prep: embedT, ee, hi/lo fragments of B' = -2*embed
__global__ void prep_kernel(const float* __restrict__ embed,
                            float* __restrict__ embedT,
                            float* __restrict__ ee,
                            uint4* __restrict__ BfragG,
                            float* __restrict__ ws_diff) {
    int tid = blockIdx.x * 256 + threadIdx.x;      // 0..16383
    if (tid == 0) ws_diff[0] = 0.f;
    for (int i = 0; i < 4; ++i) {
        int id = i * 16384 + tid;
        int d = id >> 10, e = id & 1023;
        embedT[e * 64 + d] = embed[id];
    }
    if (tid < NEMB) {
        float s = 0.f;
        for (int d = 0; d < DIM; ++d) {
            float v = embed[d * 1024 + tid];
            s = fmaf(v, v, s);
        }
        ee[tid] = s;
    }
    int fid  = tid >> 6;            // 0..255
    int lane = tid & 63;
    int hl = fid & 1, kt = (fid >> 1) & 1, ct = fid >> 2;
    int col = ct * 16 + (lane & 15);
    int k0  = kt * 32 + (lane >> 4) * 8;
    unsigned short u[8];
    #pragma unroll
    for (int j = 0; j < 8; ++j) {
        float v = -2.0f * embed[(k0 + j) * 1024 + col];
        unsigned short h = f2bf(v);
        if (hl) h = f2bf(v - bf2f(h));
        u[j] = h;
    }
    uint4 wv;
    wv.x = (unsigned)u[0] | ((unsigned)u[1] << 16);
    wv.y = (unsigned)u[2] | ((unsigned)u[3] << 16);
    wv.z = (unsigned)u[4] | ((unsigned)u[5] << 16);
    wv.w = (unsigned)u[6] | ((unsigned)u[7] << 16);
    BfragG[fid * 64 + lane] = wv;
}

// ---------------- dist: hi/lo MFMA + key-argmin + quantize + diff + recheck
__global__ __launch_bounds__(256) void dist_kernel(
        const float* __restrict__ x, const uint4* __restrict__ BfragG,
        const float* __restrict__ ee, const float* __restrict__ embed,
        const float* __restrict__ embedT,
        float* __restrict__ out_q, float* __restrict__ out_ind,
        int* __restrict__ ws_idx, float* __restrict__ ws_diff) {
    __shared__ float sEE[1024];           // 4 KB
    __shared__ int   sIdx[128];
    __shared__ float red[4];
    __shared__ int   sFlagCnt;
    __shared__ int   sFlagRows[128];
    __shared__ float sx[8][64];           // recheck stage
    __shared__ float sff[8];
    __shared__ float sbdw[8][4];
    __shared__ int   sbiw[8][4];
    __shared__ int   schg[8];

    const int t = threadIdx.x;
    const int w = t >> 6, lane = t & 63;
    const int quad = lane >> 4, wl = lane & 15;
    const int rbase = blockIdx.x * 128;

    short8 a_hi[2][2], a_lo[2][2];
    #pragma unroll
    for (int rt = 0; rt < 2; ++rt) {
        int row = rbase + w * 32 + rt * 16 + wl;
        #pragma unroll
        for (int kt = 0; kt < 2; ++kt) {
            const float* px = x + (size_t)row * 64 + kt * 32 + quad * 8;
            float4 v0 = *(const float4*)px;
            float4 v1 = *(const float4*)(px + 4);
            float vv[8] = {v0.x, v0.y, v0.z, v0.w, v1.x, v1.y, v1.z, v1.w};
            short8 ah, al;
            #pragma unroll
            for (int j = 0; j < 8; ++j) {
                unsigned short h = f2bf(vv[j]);
                ah[j] = (short)h;
                al[j] = (short)f2bf(vv[j] - bf2f(h));
            }
            a_hi[rt][kt] = ah; a_lo[rt][kt] = al;
        }
    }

    for (int i = t; i < 1024; i += 256) sEE[i] = ee[i];
    if (t == 0) sFlagCnt = 0;

    float b1[8], b2[8];
    #pragma unroll
    for (int s = 0; s < 8; ++s) { b1[s] = 3.4e38f; b2[s] = 3.4e38f; }

    const f32x4 zacc = {0.f, 0.f, 0.f, 0.f};

    __syncthreads();                      // sEE+sFlagCnt visible

#define GBODY(CB0, CB1, CB2, CB3, COLV)                                        \
    {                                                                          \
        short8 bh0 = __builtin_bit_cast(short8, CB0);                          \
        short8 bl0 = __builtin_bit_cast(short8, CB1);                          \
        short8 bh1 = __builtin_bit_cast(short8, CB2);                          \
        short8 bl1 = __builtin_bit_cast(short8, CB3);                          \
        float eec = sEE[COLV];                                                 \
        unsigned colu = (unsigned)(COLV);                                      \
        _Pragma("unroll")                                                      \
        for (int rt = 0; rt < 2; ++rt) {                                       \
            f32x4 c0 = __builtin_amdgcn_mfma_f32_16x16x32_bf16(a_lo[rt][0], bh0, zacc, 0, 0, 0); \
            f32x4 c1 = __builtin_amdgcn_mfma_f32_16x16x32_bf16(a_lo[rt][1], bh1, zacc, 0, 0, 0); \
            c0 = __builtin_amdgcn_mfma_f32_16x16x32_bf16(a_hi[rt][0], bl0, c0, 0, 0, 0); \
            c1 = __builtin_amdgcn_mfma_f32_16x16x32_bf16(a_hi[rt][1], bl1, c1, 0, 0, 0); \
            c0 = __builtin_amdgcn_mfma_f32_16x16x32_bf16(a_hi[rt][0], bh0, c0, 0, 0, 0); \
            c1 = __builtin_amdgcn_mfma_f32_16x16x32_bf16(a_hi[rt][1], bh1, c1, 0, 0, 0); \
            _Pragma("unroll")                                                  \
            for (int reg = 0; reg < 4; ++reg) {                                \
                float s = c0[reg] + c1[reg] + eec;                             \
                unsigned ku = ((__builtin_bit_cast(unsigned, s) + 0x200u) & KMASK) | colu; \
                float key = __builtin_bit_cast(float, ku);                     \
                int st = rt * 4 + reg;                                         \
                b2[st] = __builtin_amdgcn_fmed3f(key, b1[st], b2[st]);         \
                b1[st] = fminf(key, b1[st]);                                   \
            }                                                                  \
        }                                                                      \
    }

#define LOADB(S0, S1, S2, S3, P)                                               \
    { const uint4* _p = (P); S0 = _p[0]; S1 = _p[64]; S2 = _p[128]; S3 = _p[192]; }

    // main loop: 64 col-groups of 16 cols; linear walk, 4-deep prefetch.
    {
        const uint4* pa = BfragG + lane;
        uint4 A0, A1, A2, A3, B0, B1, B2, B3;
        uint4 C0, C1, C2, C3, D0, D1, D2, D3;
        LOADB(A0, A1, A2, A3, pa);
        LOADB(B0, B1, B2, B3, pa + 256);
        LOADB(C0, C1, C2, C3, pa + 512);
        LOADB(D0, D1, D2, D3, pa + 768);
        int col = wl;
        for (int it = 0; it < 64; it += 4) {
            GBODY(A0, A1, A2, A3, col);
            if (it + 4 < 64) LOADB(A0, A1, A2, A3, pa + (it + 4) * 256);
            GBODY(B0, B1, B2, B3, col + 16);
            if (it + 5 < 64) LOADB(B0, B1, B2, B3, pa + (it + 5) * 256);
            GBODY(C0, C1, C2, C3, col + 32);
            if (it + 6 < 64) LOADB(C0, C1, C2, C3, pa + (it + 6) * 256);
            GBODY(D0, D1, D2, D3, col + 48);
            if (it + 7 < 64) LOADB(D0, D1, D2, D3, pa + (it + 7) * 256);
            col += 64;
        }
    }
#undef GBODY
#undef LOADB

    // cross-lane reduce over the 16 wl lanes; keys carry the index.
    for (int m = 1; m < 16; m <<= 1) {
        #pragma unroll
        for (int s = 0; s < 8; ++s) {
            float o1 = __shfl_xor(b1[s], m);
            float o2 = __shfl_xor(b2[s], m);
            float mx = fmaxf(b1[s], o1);
            b1[s] = fminf(b1[s], o1);
            b2[s] = fminf(fminf(b2[s], o2), mx);
        }
    }
    if (wl == 0) {
        #pragma unroll
        for (int s = 0; s < 8; ++s) {
            int rt = s >> 2, reg = s & 3;
            int rloc = w * 32 + rt * 16 + quad * 4 + reg;
            int row = rbase + rloc;
            unsigned kb = __builtin_bit_cast(unsigned, b1[s]);
            int col = (int)(kb & 1023u);
            sIdx[rloc] = col;
            ws_idx[row] = col;
            out_ind[row] = (float)col;
            float v1 = __builtin_bit_cast(float, kb & KMASK);
            float v2 = __builtin_bit_cast(float, __builtin_bit_cast(unsigned, b2[s]) & KMASK);
            if (v2 - v1 < TAUK) {
                int p = atomicAdd(&sFlagCnt, 1);
                sFlagRows[p] = rloc;               // p < 128 guaranteed
            }
        }
    }
    __syncthreads();

    // quantize + diff epilogue (old indices; flagged rows fixed below)
    {
        int r = t >> 1, hh = t & 1;
        int e = sIdx[r];
        const float4* et = (const float4*)(embedT + e * 64 + hh * 32);
        const float4* xr = (const float4*)(x + (size_t)(rbase + r) * 64 + hh * 32);
        float4*       qo = (float4*)(out_q + (size_t)(rbase + r) * 64 + hh * 32);
        float dsum = 0.f;
        #pragma unroll
        for (int v = 0; v < 8; ++v) {
            float4 q4 = et[v];
            float4 x4 = xr[v];
            float dx = q4.x - x4.x, dy = q4.y - x4.y, dz = q4.z - x4.z, dw = q4.w - x4.w;
            float4 o;
            o.x = x4.x + dx; o.y = x4.y + dy; o.z = x4.z + dz; o.w = x4.w + dw;
            qo[v] = o;
            dsum += dx * dx + dy * dy + dz * dz + dw * dw;
        }
        for (int o2 = 32; o2 > 0; o2 >>= 1) dsum += __shfl_down(dsum, o2);
        if (lane == 0) red[w] = dsum;
        __syncthreads();
        if (t == 0) atomicAdd(ws_diff, red[0] + red[1] + red[2] + red[3]);
    }

    // fused recheck: exact fp32 re-argmin for flagged rows, batches of 8.
    __syncthreads();                       // quantize stores drained
    int fcnt = sFlagCnt;
    for (int base = 0; base < fcnt; base += 8) {
        int nr = fcnt - base; if (nr > 8) nr = 8;
        __syncthreads();                   // sx reuse guard
        for (int l = t; l < nr * 64; l += 256) {
            int rl = sFlagRows[base + (l >> 6)];
            sx[l >> 6][l & 63] = x[(size_t)(rbase + rl) * 64 + (l & 63)];
        }
        __syncthreads();
        if (t < nr) {
            float ff = 0.f;
            for (int k = 0; k < 64; ++k) ff = fmaf(sx[t][k], sx[t][k], ff);
            sff[t] = ff;
        }
        float acc[8][4];
        #pragma unroll
        for (int r = 0; r < 8; ++r)
            #pragma unroll
            for (int j = 0; j < 4; ++j) acc[r][j] = 0.f;
        int c0i = t * 4;
        for (int k = 0; k < 64; ++k) {
            float4 e4 = *(const float4*)(embed + k * 1024 + c0i);
            #pragma unroll
            for (int r = 0; r < 8; ++r) {
                float xk = sx[r][k];
                acc[r][0] = fmaf(xk, e4.x, acc[r][0]);
                acc[r][1] = fmaf(xk, e4.y, acc[r][1]);
                acc[r][2] = fmaf(xk, e4.z, acc[r][2]);
                acc[r][3] = fmaf(xk, e4.w, acc[r][3]);
            }
        }
        __syncthreads();                   // sff visible
        #pragma unroll
        for (int r = 0; r < 8; ++r) {
            if (r < nr) {
                float ff = sff[r];
                float bd = 3.4e38f; int bi = 0;
                #pragma unroll
                for (int j = 0; j < 4; ++j) {
                    float d = (ff - 2.f * acc[r][j]) + sEE[c0i + j];
                    if (d < bd) { bd = d; bi = c0i + j; }
                }
                for (int m = 32; m > 0; m >>= 1) {
                    float od = __shfl_xor(bd, m);
                    int   oi = __shfl_xor(bi, m);
                    if (od < bd || (od == bd && oi < bi)) { bd = od; bi = oi; }
                }
                if (lane == 0) { sbdw[r][w] = bd; sbiw[r][w] = bi; }
            }
        }
        __syncthreads();
        if (t < nr) {
            float bd = sbdw[t][0]; int bi = sbiw[t][0];
            #pragma unroll
            for (int k2 = 1; k2 < 4; ++k2) {
                float od = sbdw[t][k2]; int oi = sbiw[t][k2];
                if (od < bd || (od == bd && oi < bi)) { bd = od; bi = oi; }
            }
            int rl = sFlagRows[base + t];
            int oi_ = sIdx[rl];
            schg[t] = (bi != oi_) ? bi : -1;
            if (bi != oi_) {
                ws_idx[rbase + rl] = bi;
                out_ind[rbase + rl] = (float)bi;
            }
        }
        __syncthreads();
        for (int r = w; r < nr; r += 4) {
            int ni = schg[r];
            if (ni >= 0) {
                int rl = sFlagRows[base + r];
                int row = rbase + rl;
                int oi_ = sIdx[rl];
                float xv = sx[r][lane];
                float dn   = embedT[ni * 64 + lane] - xv;
                float dold = embedT[oi_ * 64 + lane] - xv;
                out_q[(size_t)row * 64 + lane] = xv + dn;
                float delta = dn * dn - dold * dold;
                for (int o = 32; o > 0; o >>= 1) delta += __shfl_down(delta, o);
                if (lane == 0) atomicAdd(ws_diff, delta);
            }
        }
    }
}

// ---------------- scatter: 32 ranges x 8 dim-octants (R15 form)
__global__ __launch_bounds__(1024) void scatter_kernel(
        const int* __restrict__ idx, const float* __restrict__ x,
        float* __restrict__ part_or_esum, float* __restrict__ cntp_or_cntf,
        int use_atomic) {
    __shared__ float shist[8192];         // [1024 codes][8 dims] = 32 KB
    __shared__ float scnt[1024];
    const int t = threadIdx.x;
    const int bid = blockIdx.x;
    const int oct = (bid >> 3) & 7;
    const int rb  = (bid & 7) | ((bid >> 6) << 3);
    const int sid = rb * 8 + oct;
    const int w = t >> 6, lane = t & 63;
    const int g = lane >> 3, d = lane & 7;

    for (int i = t; i < 8192; i += 1024) shist[i] = 0.f;
    if (oct == 0) { if (t < 1024) scnt[t] = 0.f; }
    __syncthreads();

    const int row0 = rb * 4096 + w * 256;
    int rcur = row0 + g;
    int e_n = idx[rcur];
    float x_n = x[(size_t)rcur * 64 + oct * 8 + d];
    for (int it = 0; it < 32; ++it) {
        int e = e_n; float xv = x_n;
        int rnext = rcur + 8;
        if (it < 31) {
            e_n = idx[rnext];
            x_n = x[(size_t)rnext * 64 + oct * 8 + d];
        }
        rcur = rnext;
        atomicAdd(&shist[e * 8 + d], xv);
        if (oct == 0 && d == 0) atomicAdd(&scnt[e], 1.0f);
    }
    __syncthreads();

    if (!use_atomic) {
        float* dst = part_or_esum + (size_t)sid * 8192;
        for (int out = t; out < 8192; out += 1024)
            dst[out] = shist[(out & 1023) * 8 + (out >> 10)];
        if (oct == 0) {
            float* cdst = cntp_or_cntf + rb * 1024;
            if (t < 1024) cdst[t] = scnt[t];
        }
    } else {
        for (int out = t; out < 8192; out += 1024) {
            float v = shist[(out & 1023) * 8 + (out >> 10)];
            if (v != 0.f)
                atomicAdd(&part_or_esum[(oct * 8 + (out >> 10)) * 1024 + (out & 1023)], v);
        }
        if (oct == 0) {
            if (t < 1024) {
                float c = scnt[t];
                if (c != 0.f) atomicAdd(&cntp_or_cntf[t], c);
            }
        }
    }
}

// ---------------- finalizeF: fused finalize1+finalize2 (64 blocks x 1024)
__global__ __launch_bounds__(1024) void finalizeF(
        const float* __restrict__ cluster_size, const float* __restrict__ cntp,
        const float* __restrict__ part, int nrb,
        const float* __restrict__ ws_diff, const float* __restrict__ embed_avg,
        float* __restrict__ out_diff, float* __restrict__ out_ncs,
        float* __restrict__ out_nea, float* __restrict__ out_ne) {
    __shared__ float sred[16];
    __shared__ float sn;
    const int tid = threadIdx.x;
    const int b = blockIdx.x;
    float c = 0.f;
    for (int k = 0; k < nrb; ++k) c += cntp[k * 1024 + tid];
    float ncs = DECAYF * cluster_size[tid] + OMDF * c;
    float v = ncs;
    for (int o = 32; o > 0; o >>= 1) v += __shfl_down(v, o);
    if ((tid & 63) == 0) sred[tid >> 6] = v;
    __syncthreads();
    if (tid == 0) {
        float n = 0.f;
        for (int i = 0; i < 16; ++i) n += sred[i];
        sn = n;
        if (b == 0) out_diff[0] = ws_diff[0] * (1.0f / 8388608.0f);
    }
    __syncthreads();
    float n = sn;
    if (b == 0) out_ncs[tid] = ncs;
    int j = b * 1024 + tid;                       // dim = b, code = tid
    float es = 0.f;
    for (int k = 0; k < nrb; ++k) es += part[(size_t)k * 65536 + j];
    float nea = DECAYF * embed_avg[j] + OMDF * es;
    out_nea[j] = nea;
    float cs = (ncs + EPSF) / (n + NEPSF) * n;
    out_ne[j] = nea / cs;
}

extern "C" void kernel_launch(void* const* d_in, const int* in_sizes, int n_in,
                              void* d_out, int out_size, void* d_ws, size_t ws_size,
                              hipStream_t stream) {
    const float* x            = (const float*)d_in[0];
    const float* embed        = (const float*)d_in[1];
    const float* cluster_size = (const float*)d_in[2];
    const float* embed_avg    = (const float*)d_in[3];

    float* out = (float*)d_out;
    float* out_q    = out;                       // 8388608
    float* out_diff = out + 8388608;             // 1
    float* out_ind  = out + 8388609;             // 131072
    float* out_ncs  = out + 8519681;             // 1024
    float* out_nea  = out + 8520705;             // 65536
    float* out_ne   = out + 8586241;             // 65536

    float* ws = (float*)d_ws;
    float* ws_esum     = ws + WS_ESUM;
    float* ws_cntf     = ws + WS_CNTF;
    float* ws_diff     = ws + WS_DIFF;
    float* ws_ee       = ws + WS_EE;
    float* ws_embedT   = ws + WS_EMBEDT;
    int*   ws_idx      = (int*)(ws + WS_IDX);
    uint4* ws_Bfrag    = (uint4*)(ws + WS_BFRAG);
    float* ws_cntpart  = ws + WS_CNTPART;
    float* ws_part     = ws + WS_PART;

    const int use_part = (ws_size >= WS_NEED_BYTES) ? 1 : 0;

    if (!use_part) {
        // atomic fallback needs zeroed esum/cntf (+diff)
        hipMemsetAsync(d_ws, 0, (size_t)(WS_FLAGCNT + 1) * 4, stream);
    }

    prep_kernel<<<64, 256, 0, stream>>>(embed, ws_embedT, ws_ee, ws_Bfrag, ws_diff);
    dist_kernel<<<N_ROWS / 128, 256, 0, stream>>>(x, ws_Bfrag, ws_ee, embed,
                                                  ws_embedT, out_q, out_ind,
                                                  ws_idx, ws_diff);
    scatter_kernel<<<NRANGE * 8, 1024, 0, stream>>>(
        ws_idx, x,
        use_part ? ws_part : ws_esum,
        use_part ? ws_cntpart : ws_cntf,
        use_part ? 0 : 1);
    finalizeF<<<64, 1024, 0, stream>>>(cluster_size,
                                       use_part ? ws_cntpart : ws_cntf,
                                       use_part ? ws_part : ws_esum,
                                       use_part ? NRANGE : 1,
                                       ws_diff, embed_avg,
                                       out_diff, out_ncs, out_nea, out_ne);
}